// Round 1
// baseline (395.585 us; speedup 1.0000x reference)
//
#include <hip/hip_runtime.h>

// MQA fused layer, MI355X gfx950.
// B=4 T=4096 C=1024 H=16 D=64 W=128 NB=32.
// Pipeline: cvt(x)->bf16 | transpose-cvt weights | GEMM qkv (bf16 MFMA) |
//           RMS+RoPE q,k | blocked sliding-window attention | GEMM proj.

typedef __attribute__((ext_vector_type(8))) short short8;
typedef __attribute__((ext_vector_type(4))) float f32x4;
typedef __attribute__((ext_vector_type(16))) float f32x16;

#define DEV static __device__ __forceinline__

DEV unsigned short f2bf(float f) {           // fp32 -> bf16 RNE
  unsigned u = __builtin_bit_cast(unsigned, f);
  u += 0x7fffu + ((u >> 16) & 1u);
  return (unsigned short)(u >> 16);
}
DEV float bf2f(unsigned short s) {
  unsigned u = ((unsigned)s) << 16;
  return __builtin_bit_cast(float, u);
}

// MFMA wrappers (single place to switch operand vector type if needed)
DEV f32x4 mfma16(short8 a, short8 b, f32x4 c) {
  return __builtin_amdgcn_mfma_f32_16x16x32_bf16(a, b, c, 0, 0, 0);
}
DEV f32x16 mfma32(short8 a, short8 b, f32x16 c) {
  return __builtin_amdgcn_mfma_f32_32x32x16_bf16(a, b, c, 0, 0, 0);
}

// async global->LDS, 16B per lane
DEV void gload16(const void* g, void* l) {
  __builtin_amdgcn_global_load_lds(
      (const __attribute__((address_space(1))) unsigned int*)(unsigned long long)g,
      (__attribute__((address_space(3))) unsigned int*)(unsigned int)(unsigned long long)l,
      16, 0, 0);
}

// ---------------- kernel: f32 -> bf16 elementwise ----------------
__global__ __launch_bounds__(256) void k_cvt(const float* __restrict__ in,
                                             short* __restrict__ out, int n4) {
  int i = blockIdx.x * 256 + threadIdx.x;
  if (i >= n4) return;
  float4 v = ((const float4*)in)[i];
  short4 o;
  o.x = (short)f2bf(v.x); o.y = (short)f2bf(v.y);
  o.z = (short)f2bf(v.z); o.w = (short)f2bf(v.w);
  ((short4*)out)[i] = o;
}

// ---------------- kernel: W (KxN f32) -> Wt (NxK bf16) ----------------
__global__ __launch_bounds__(256) void k_tcvt(const float* __restrict__ W,
                                              short* __restrict__ Wt, int K, int N) {
  __shared__ float tl[32][33];
  int tx = threadIdx.x & 31, ty = threadIdx.x >> 5;   // 32 x 8
  int k0 = blockIdx.x * 32, n0 = blockIdx.y * 32;
#pragma unroll
  for (int i = 0; i < 4; ++i)
    tl[ty + i * 8][tx] = W[(size_t)(k0 + ty + i * 8) * N + n0 + tx];
  __syncthreads();
#pragma unroll
  for (int i = 0; i < 4; ++i)
    Wt[(size_t)(n0 + ty + i * 8) * K + k0 + tx] = (short)f2bf(tl[tx][ty + i * 8]);
}

// ---------------- kernel: 128x128x32 bf16 GEMM (m97 structure) ----------------
// A: MxK row-major bf16. Bt: NxK row-major bf16 (pre-transposed B). C: MxN.
__global__ __launch_bounds__(256) void k_gemm(const short* __restrict__ A,
                                              const short* __restrict__ Bt,
                                              void* __restrict__ Cout,
                                              int M, int N, int K, int outBf16) {
  __shared__ short As[128 * 32];
  __shared__ short Bs[128 * 32];
  int nbn = N >> 7;
  int nwg = (M >> 7) * nbn;
  int bid = blockIdx.x;
  int swz = (bid & 7) * (nwg >> 3) + (bid >> 3);   // XCD swizzle (nwg % 8 == 0)
  int bn = swz % nbn, bm = swz / nbn;
  int tid = threadIdx.x, lane = tid & 63, wid = tid >> 6;
  int wr = wid >> 1, wc = wid & 1;
  int lo = lane & 15, hi = lane >> 4;
  const short* Ab = A + (size_t)(bm * 128 + (tid >> 2)) * K + (tid & 3) * 8;
  const short* Bb = Bt + (size_t)(bn * 128 + (tid >> 2)) * K + (tid & 3) * 8;
  f32x4 acc[4][4] = {};
  for (int kt = 0; kt < K; kt += 32) {
    gload16(Ab + kt,            As + tid * 8);
    gload16(Ab + kt + 64 * K,   As + 2048 + tid * 8);
    gload16(Bb + kt,            Bs + tid * 8);
    gload16(Bb + kt + 64 * K,   Bs + 2048 + tid * 8);
    __syncthreads();
    short8 a[4], b[4];
#pragma unroll
    for (int m = 0; m < 4; ++m)
      a[m] = *(const short8*)&As[(wr * 64 + m * 16 + lo) * 32 + hi * 8];
#pragma unroll
    for (int n = 0; n < 4; ++n)
      b[n] = *(const short8*)&Bs[(wc * 64 + n * 16 + lo) * 32 + hi * 8];
#pragma unroll
    for (int m = 0; m < 4; ++m)
#pragma unroll
      for (int n = 0; n < 4; ++n)
        acc[m][n] = mfma16(a[m], b[n], acc[m][n]);
    __syncthreads();
  }
  // C layout (verified): col = lane&15, row = (lane>>4)*4 + reg
  int row0 = bm * 128 + wr * 64 + hi * 4;
  int col0 = bn * 128 + wc * 64 + lo;
  if (outBf16) {
    short* C = (short*)Cout;
#pragma unroll
    for (int m = 0; m < 4; ++m)
#pragma unroll
      for (int n = 0; n < 4; ++n)
#pragma unroll
        for (int r = 0; r < 4; ++r)
          C[(size_t)(row0 + m * 16 + r) * N + col0 + n * 16] = (short)f2bf(acc[m][n][r]);
  } else {
    float* C = (float*)Cout;
#pragma unroll
    for (int m = 0; m < 4; ++m)
#pragma unroll
      for (int n = 0; n < 4; ++n)
#pragma unroll
        for (int r = 0; r < 4; ++r)
          C[(size_t)(row0 + m * 16 + r) * N + col0 + n * 16] = acc[m][n][r];
  }
}

// ---------------- kernel: RMSNorm + RoPE for q (16 heads) and k ----------------
// one wave (64 lanes = D) per token
__global__ __launch_bounds__(64) void k_qk(const short* __restrict__ qkvb,
                                           const int* __restrict__ pos,
                                           const float* __restrict__ qw,
                                           const float* __restrict__ kw,
                                           short* __restrict__ qb,
                                           short* __restrict__ kb) {
  int bt = blockIdx.x;           // b*4096 + t
  int t = bt & 4095, b = bt >> 12;
  int d = threadIdx.x;           // 0..63
  int j = d & 31;
  // inv_freq = 1e6^(-j/32); cos/sin computed once per token, shared across rows
  float invf = __expf((float)j * (-13.815510558f / 32.f));
  float sn, cs;
  sincosf((float)pos[t * 3 + (j % 3)] * invf, &sn, &cs);
  const short* base = qkvb + (size_t)bt * 1152;
  float wq = qw[d], wk = kw[d];

  auto rowproc = [&](float x, float w) -> float {
    float ss = x * x;
    ss += __shfl_xor(ss, 1);  ss += __shfl_xor(ss, 2);  ss += __shfl_xor(ss, 4);
    ss += __shfl_xor(ss, 8);  ss += __shfl_xor(ss, 16); ss += __shfl_xor(ss, 32);
    float xn = x * rsqrtf(ss * 0.015625f + 1e-6f) * w;
    float pr = __shfl_xor(xn, 32);                 // RoPE partner d +- 32
    return (d < 32) ? xn * cs - pr * sn : xn * cs + pr * sn;
  };
  {
    float x = bf2f((unsigned short)base[1024 + d]);
    kb[(size_t)bt * 64 + d] = (short)f2bf(rowproc(x, wk));
  }
#pragma unroll 4
  for (int hh = 0; hh < 16; ++hh) {
    float x = bf2f((unsigned short)base[hh * 64 + d]);
    qb[((size_t)((b * 16 + hh) * 4096 + t)) * 64 + d] = (short)f2bf(rowproc(x, wq));
  }
}

// ---------------- kernel: blocked sliding-window attention ----------------
// grid 2048 = (b, n, h fastest). block = 4 waves; wave w owns query rows w*32..w*32+31.
// two 128-key halves, online softmax. LDS exactly 64KB.
__global__ __launch_bounds__(256, 2) void k_attn(const short* __restrict__ qb,
                                                 const short* __restrict__ kb,
                                                 const short* __restrict__ qkvb,
                                                 short* __restrict__ y) {
  __shared__ short ks[128 * 64];    // K half: [key][d], 16B-chunk XOR swizzle
  __shared__ short vts[64 * 128];   // V^T half: [d][key], swizzled
  __shared__ short ps[4 * 32 * 128];// P per wave: [qrow][key], swizzled
  int bid = blockIdx.x;
  int swz = (bid & 7) * 256 + (bid >> 3);          // XCD swizzle
  int h = swz & 15, n = (swz >> 4) & 31, b = swz >> 9;
  int tid = threadIdx.x, wid = tid >> 6, lane = tid & 63;
  int lo = lane & 31, hi = lane >> 5;

  // Q fragments in registers: A-layout row=lane&31, k = 8*hi + j within 16-step
  const short* qrow = qb + (size_t)((b * 16 + h) * 4096 + n * 128 + wid * 32 + lo) * 64;
  short8 aq[4];
#pragma unroll
  for (int s = 0; s < 4; ++s) aq[s] = *(const short8*)(qrow + s * 16 + hi * 8);

  f32x16 O0 = {}, O1 = {};
  float mrun[16], lrun[16];
#pragma unroll
  for (int r = 0; r < 16; ++r) { mrun[r] = -1e30f; lrun[r] = 0.f; }

  for (int hf = (n == 0) ? 1 : 0; hf < 2; ++hf) {  // n==0: half0 fully masked, skip
    int t0 = b * 4096 + (n - 1 + hf) * 128;        // first key token of this half
    // stage K half: [key r][d], swizzled chunk = dc ^ (r&7)
#pragma unroll
    for (int p = 0; p < 4; ++p) {
      int idx = p * 256 + tid;
      int r = idx >> 3, dc = idx & 7;
      short8 kv = *(const short8*)(kb + (size_t)(t0 + r) * 64 + dc * 8);
      *(short8*)&ks[r * 64 + ((dc ^ (r & 7)) << 3)] = kv;
    }
    // stage V^T half from qkv slice (cols 1088..1151)
#pragma unroll
    for (int p = 0; p < 4; ++p) {
      int idx = p * 256 + tid;
      int dc = idx >> 7, tl = idx & 127;
      short8 vv = *(const short8*)(qkvb + (size_t)(t0 + tl) * 1152 + 1088 + dc * 8);
#pragma unroll
      for (int jj = 0; jj < 8; ++jj) {
        int dd = dc * 8 + jj;
        vts[dd * 128 + ((((tl >> 3) ^ (dd & 7))) << 3) + (tl & 7)] = vv[jj];
      }
    }
    __syncthreads();

    // S = Q * K^T  (4 col-tiles of 32 keys, 4 k-steps of d=16)
    f32x16 S[4] = {};
#pragma unroll
    for (int ct = 0; ct < 4; ++ct)
#pragma unroll
      for (int kst = 0; kst < 4; ++kst) {
        int r = ct * 32 + lo;
        short8 bk = *(const short8*)&ks[r * 64 + ((((kst << 1) + hi) ^ (r & 7)) << 3)];
        S[ct] = mfma32(aq[kst], bk, S[ct]);
      }
    // mask + scale. qr,kg in block-local 256-key space: valid iff qr <= kg <= qr+128
#pragma unroll
    for (int ct = 0; ct < 4; ++ct)
#pragma unroll
      for (int r = 0; r < 16; ++r) {
        int qr = wid * 32 + (r & 3) + ((r >> 2) << 3) + 4 * hi;
        int kg = hf * 128 + ct * 32 + lo;
        S[ct][r] = (kg >= qr && kg <= qr + 128) ? S[ct][r] * 0.125f : -1e30f;
      }
    // row max (over 4 tiles + 32 lanes) and online rescale
#pragma unroll
    for (int r = 0; r < 16; ++r) {
      float v = fmaxf(fmaxf(S[0][r], S[1][r]), fmaxf(S[2][r], S[3][r]));
      v = fmaxf(v, __shfl_xor(v, 1));  v = fmaxf(v, __shfl_xor(v, 2));
      v = fmaxf(v, __shfl_xor(v, 4));  v = fmaxf(v, __shfl_xor(v, 8));
      v = fmaxf(v, __shfl_xor(v, 16));
      float mn = fmaxf(mrun[r], v);
      float al = __expf(mrun[r] - mn);
      mrun[r] = mn; lrun[r] *= al; O0[r] *= al; O1[r] *= al;
    }
    // exp, row-sum, write P (bf16) to per-wave LDS
#pragma unroll
    for (int r = 0; r < 16; ++r) {
      int prow = (r & 3) + ((r >> 2) << 3) + 4 * hi;
      float ts = 0.f;
#pragma unroll
      for (int ct = 0; ct < 4; ++ct) {
        float pv = __expf(S[ct][r] - mrun[r]);
        ts += pv;
        int col = ct * 32 + lo;
        ps[wid * 4096 + prow * 128 + (((col >> 3) ^ (prow & 7)) << 3) + (col & 7)] =
            (short)f2bf(pv);
      }
      ts += __shfl_xor(ts, 1);  ts += __shfl_xor(ts, 2);  ts += __shfl_xor(ts, 4);
      ts += __shfl_xor(ts, 8);  ts += __shfl_xor(ts, 16);
      lrun[r] += ts;
    }
    __threadfence_block();   // order P ds_writes before PV ds_reads (same wave)
    // O += P * V  (8 k-steps of 16 keys, 2 d-tiles)
#pragma unroll
    for (int kst = 0; kst < 8; ++kst) {
      short8 pa = *(const short8*)&ps[wid * 4096 + lo * 128 +
                                      ((((kst << 1) + hi) ^ (lo & 7)) << 3)];
      {
        int dd = lo;
        short8 vb = *(const short8*)&vts[dd * 128 + ((((kst << 1) + hi) ^ (dd & 7)) << 3)];
        O0 = mfma32(pa, vb, O0);
      }
      {
        int dd = 32 + lo;
        short8 vb = *(const short8*)&vts[dd * 128 + ((((kst << 1) + hi) ^ (dd & 7)) << 3)];
        O1 = mfma32(pa, vb, O1);
      }
    }
    __syncthreads();   // protect ks/vts before next half's staging
  }
  // epilogue: divide by l, write y as (B,T,H*D) bf16
  int tq = n * 128 + wid * 32;
#pragma unroll
  for (int r = 0; r < 16; ++r) {
    int row = (r & 3) + ((r >> 2) << 3) + 4 * hi;
    float inv = 1.f / lrun[r];
    size_t baseo = ((size_t)(b * 4096 + tq + row)) * 1024 + h * 64;
    y[baseo + lo]      = (short)f2bf(O0[r] * inv);
    y[baseo + 32 + lo] = (short)f2bf(O1[r] * inv);
  }
}

// ---------------- launch ----------------
extern "C" void kernel_launch(void* const* d_in, const int* in_sizes, int n_in,
                              void* d_out, int out_size, void* d_ws, size_t ws_size,
                              hipStream_t stream) {
  const float* x      = (const float*)d_in[0];
  const int*   pos    = (const int*)d_in[1];
  const float* w_attn = (const float*)d_in[2];
  const float* w_proj = (const float*)d_in[3];
  const float* qw     = (const float*)d_in[4];
  const float* kw     = (const float*)d_in[5];

  char* ws = (char*)d_ws;
  short* xb   = (short*)ws;                         // 33,554,432 B (aliased as y later)
  short* wabt = (short*)(ws + 33554432);            //  2,359,296 B
  short* wpbt = (short*)(ws + 35913728);            //  2,097,152 B
  short* qkvb = (short*)(ws + 38010880);            // 37,748,736 B
  short* qb2  = (short*)(ws + 75759616);            // 33,554,432 B
  short* kb2  = (short*)(ws + 109314048);           //  2,097,152 B  (total 111.4 MB)
  short* ybuf = xb;                                 // xb dead after qkv GEMM

  hipLaunchKernelGGL(k_cvt, dim3(16384), dim3(256), 0, stream, x, xb, 4194304);
  hipLaunchKernelGGL(k_tcvt, dim3(32, 36), dim3(256), 0, stream, w_attn, wabt, 1024, 1152);
  hipLaunchKernelGGL(k_tcvt, dim3(32, 32), dim3(256), 0, stream, w_proj, wpbt, 1024, 1024);
  hipLaunchKernelGGL(k_gemm, dim3(1152), dim3(256), 0, stream, xb, wabt, (void*)qkvb,
                     16384, 1152, 1024, 1);
  hipLaunchKernelGGL(k_qk, dim3(16384), dim3(64), 0, stream, qkvb, pos, qw, kw, qb2, kb2);
  hipLaunchKernelGGL(k_attn, dim3(2048), dim3(256), 0, stream, qb2, kb2, qkvb, ybuf);
  hipLaunchKernelGGL(k_gemm, dim3(1024), dim3(256), 0, stream, ybuf, wpbt, d_out,
                     16384, 1024, 1024, 0);
}

// Round 2
// 238.488 us; speedup vs baseline: 1.6587x; 1.6587x over previous
//
#include <hip/hip_runtime.h>

// MQA fused layer, MI355X gfx950.
// B=4 T=4096 C=1024 H=16 D=64 W=128 NB=32.
// Pipeline: cvt(x)->bf16 | transpose-cvt weights | GEMM qkv (bf16 MFMA) |
//           RMS+RoPE q,k | V transpose | blocked sliding-window attention
//           (swapped-QK^T, in-register softmax) | GEMM proj.

typedef __attribute__((ext_vector_type(8))) short short8;
typedef __attribute__((ext_vector_type(4))) float f32x4;
typedef __attribute__((ext_vector_type(16))) float f32x16;
typedef __attribute__((ext_vector_type(4))) unsigned uint4v;

#define DEV static __device__ __forceinline__

DEV unsigned short f2bf(float f) {           // fp32 -> bf16 RNE
  unsigned u = __builtin_bit_cast(unsigned, f);
  u += 0x7fffu + ((u >> 16) & 1u);
  return (unsigned short)(u >> 16);
}
DEV float bf2f(unsigned short s) {
  unsigned u = ((unsigned)s) << 16;
  return __builtin_bit_cast(float, u);
}
DEV unsigned cvtpk(float a, float b) {       // {bf16(a), bf16(b)} packed
  unsigned r;
  asm("v_cvt_pk_bf16_f32 %0, %1, %2" : "=v"(r) : "v"(a), "v"(b));
  return r;
}

DEV f32x4 mfma16(short8 a, short8 b, f32x4 c) {
  return __builtin_amdgcn_mfma_f32_16x16x32_bf16(a, b, c, 0, 0, 0);
}
DEV f32x16 mfma32(short8 a, short8 b, f32x16 c) {
  return __builtin_amdgcn_mfma_f32_32x32x16_bf16(a, b, c, 0, 0, 0);
}

// async global->LDS, 16B per lane
DEV void gload16(const void* g, void* l) {
  __builtin_amdgcn_global_load_lds(
      (const __attribute__((address_space(1))) unsigned int*)(unsigned long long)g,
      (__attribute__((address_space(3))) unsigned int*)(unsigned int)(unsigned long long)l,
      16, 0, 0);
}

// ---------------- kernel: f32 -> bf16 elementwise ----------------
__global__ __launch_bounds__(256) void k_cvt(const float* __restrict__ in,
                                             short* __restrict__ out, int n4) {
  int i = blockIdx.x * 256 + threadIdx.x;
  if (i >= n4) return;
  float4 v = ((const float4*)in)[i];
  short4 o;
  o.x = (short)f2bf(v.x); o.y = (short)f2bf(v.y);
  o.z = (short)f2bf(v.z); o.w = (short)f2bf(v.w);
  ((short4*)out)[i] = o;
}

// ---------------- kernel: W (KxN f32) -> Wt (NxK bf16) ----------------
__global__ __launch_bounds__(256) void k_tcvt(const float* __restrict__ W,
                                              short* __restrict__ Wt, int K, int N) {
  __shared__ float tl[32][33];
  int tx = threadIdx.x & 31, ty = threadIdx.x >> 5;   // 32 x 8
  int k0 = blockIdx.x * 32, n0 = blockIdx.y * 32;
#pragma unroll
  for (int i = 0; i < 4; ++i)
    tl[ty + i * 8][tx] = W[(size_t)(k0 + ty + i * 8) * N + n0 + tx];
  __syncthreads();
#pragma unroll
  for (int i = 0; i < 4; ++i)
    Wt[(size_t)(n0 + ty + i * 8) * K + k0 + tx] = (short)f2bf(tl[tx][ty + i * 8]);
}

// ---------------- kernel: 128x128x32 bf16 GEMM (m97 structure) ----------------
__global__ __launch_bounds__(256) void k_gemm(const short* __restrict__ A,
                                              const short* __restrict__ Bt,
                                              void* __restrict__ Cout,
                                              int M, int N, int K, int outBf16) {
  __shared__ short As[128 * 32];
  __shared__ short Bs[128 * 32];
  int nbn = N >> 7;
  int nwg = (M >> 7) * nbn;
  int bid = blockIdx.x;
  int swz = (bid & 7) * (nwg >> 3) + (bid >> 3);   // XCD swizzle (nwg % 8 == 0)
  int bn = swz % nbn, bm = swz / nbn;
  int tid = threadIdx.x, lane = tid & 63, wid = tid >> 6;
  int wr = wid >> 1, wc = wid & 1;
  int lo = lane & 15, hi = lane >> 4;
  const short* Ab = A + (size_t)(bm * 128 + (tid >> 2)) * K + (tid & 3) * 8;
  const short* Bb = Bt + (size_t)(bn * 128 + (tid >> 2)) * K + (tid & 3) * 8;
  f32x4 acc[4][4] = {};
  for (int kt = 0; kt < K; kt += 32) {
    gload16(Ab + kt,            As + tid * 8);
    gload16(Ab + kt + 64 * K,   As + 2048 + tid * 8);
    gload16(Bb + kt,            Bs + tid * 8);
    gload16(Bb + kt + 64 * K,   Bs + 2048 + tid * 8);
    __syncthreads();
    short8 a[4], b[4];
#pragma unroll
    for (int m = 0; m < 4; ++m)
      a[m] = *(const short8*)&As[(wr * 64 + m * 16 + lo) * 32 + hi * 8];
#pragma unroll
    for (int n = 0; n < 4; ++n)
      b[n] = *(const short8*)&Bs[(wc * 64 + n * 16 + lo) * 32 + hi * 8];
#pragma unroll
    for (int m = 0; m < 4; ++m)
#pragma unroll
      for (int n = 0; n < 4; ++n)
        acc[m][n] = mfma16(a[m], b[n], acc[m][n]);
    __syncthreads();
  }
  int row0 = bm * 128 + wr * 64 + hi * 4;
  int col0 = bn * 128 + wc * 64 + lo;
  if (outBf16) {
    short* C = (short*)Cout;
#pragma unroll
    for (int m = 0; m < 4; ++m)
#pragma unroll
      for (int n = 0; n < 4; ++n)
#pragma unroll
        for (int r = 0; r < 4; ++r)
          C[(size_t)(row0 + m * 16 + r) * N + col0 + n * 16] = (short)f2bf(acc[m][n][r]);
  } else {
    float* C = (float*)Cout;
#pragma unroll
    for (int m = 0; m < 4; ++m)
#pragma unroll
      for (int n = 0; n < 4; ++n)
#pragma unroll
        for (int r = 0; r < 4; ++r)
          C[(size_t)(row0 + m * 16 + r) * N + col0 + n * 16] = acc[m][n][r];
  }
}

// ---------------- kernel: RMSNorm + RoPE for q (16 heads) and k ----------------
__global__ __launch_bounds__(64) void k_qk(const short* __restrict__ qkvb,
                                           const int* __restrict__ pos,
                                           const float* __restrict__ qw,
                                           const float* __restrict__ kw,
                                           short* __restrict__ qb,
                                           short* __restrict__ kb) {
  int bt = blockIdx.x;           // b*4096 + t
  int t = bt & 4095, b = bt >> 12;
  int d = threadIdx.x;           // 0..63
  int j = d & 31;
  float invf = __expf((float)j * (-13.815510558f / 32.f));
  float sn, cs;
  sincosf((float)pos[t * 3 + (j % 3)] * invf, &sn, &cs);
  const short* base = qkvb + (size_t)bt * 1152;
  float wq = qw[d], wk = kw[d];

  auto rowproc = [&](float x, float w) -> float {
    float ss = x * x;
    ss += __shfl_xor(ss, 1);  ss += __shfl_xor(ss, 2);  ss += __shfl_xor(ss, 4);
    ss += __shfl_xor(ss, 8);  ss += __shfl_xor(ss, 16); ss += __shfl_xor(ss, 32);
    float xn = x * rsqrtf(ss * 0.015625f + 1e-6f) * w;
    float pr = __shfl_xor(xn, 32);                 // RoPE partner d +- 32
    return (d < 32) ? xn * cs - pr * sn : xn * cs + pr * sn;
  };
  {
    float x = bf2f((unsigned short)base[1024 + d]);
    kb[(size_t)bt * 64 + d] = (short)f2bf(rowproc(x, wk));
  }
#pragma unroll 4
  for (int hh = 0; hh < 16; ++hh) {
    float x = bf2f((unsigned short)base[hh * 64 + d]);
    qb[((size_t)((b * 16 + hh) * 4096 + t)) * 64 + d] = (short)f2bf(rowproc(x, wq));
  }
}

// ---------------- kernel: V slice of qkv -> vtg[b][64][4096] ----------------
__global__ __launch_bounds__(256) void k_vt(const short* __restrict__ qkvb,
                                            short* __restrict__ vtg) {
  __shared__ short ts[64][72];                     // 72: 16B-aligned rows
  int t0 = blockIdx.x * 64;
  int b = t0 >> 12, tl0 = t0 & 4095;
  int row = threadIdx.x >> 2, c4 = threadIdx.x & 3;
  const short* src = qkvb + (size_t)(t0 + row) * 1152 + 1088 + c4 * 16;
  *(short8*)&ts[row][c4 * 16]     = *(const short8*)src;
  *(short8*)&ts[row][c4 * 16 + 8] = *(const short8*)(src + 8);
  __syncthreads();
  short8 o0, o1;                                   // row = d, c4 = token group
#pragma unroll
  for (int jj = 0; jj < 8; ++jj) {
    o0[jj] = ts[c4 * 16 + jj][row];
    o1[jj] = ts[c4 * 16 + 8 + jj][row];
  }
  short* dst = vtg + (size_t)(b * 64 + row) * 4096 + tl0 + c4 * 16;
  *(short8*)dst = o0;
  *(short8*)(dst + 8) = o1;
}

// ---------------- kernel: blocked sliding-window attention (swapped QK^T) ----
// grid 2048 = (b, n, h fastest). 4 waves x 32 q-rows. Online softmax fully
// in-register: S^T layout puts a q-row in one lane (split across hi halves).
__global__ __launch_bounds__(256, 4) void k_attn(const short* __restrict__ qb,
                                                 const short* __restrict__ kb,
                                                 const short* __restrict__ vtg,
                                                 short* __restrict__ y) {
  __shared__ __align__(16) char smem[33792];
  short* ks  = (short*)smem;            // [128 key][64 d], chunk-XOR swizzled
  short* vts = (short*)(smem + 16384);  // [64 d][128 key], chunk-XOR swizzled
  int bid = blockIdx.x;
  int swz = (bid & 7) * 256 + (bid >> 3);          // XCD swizzle
  int h = swz & 15, n = (swz >> 4) & 31, b = swz >> 9;
  int tid = threadIdx.x, wid = tid >> 6, lane = tid & 63;
  int lo = lane & 31, hi = lane >> 5;

  // Q fragments (B-operand: col = q-row = lane&31, k-chunk = s*16 + hi*8)
  const short* qrow = qb + (size_t)((b * 16 + h) * 4096 + n * 128 + wid * 32 + lo) * 64;
  short8 aq[4];
#pragma unroll
  for (int s = 0; s < 4; ++s) aq[s] = *(const short8*)(qrow + s * 16 + hi * 8);

  f32x16 O0 = {}, O1 = {};                         // O^T: rows d / d+32, col q
  float mrun = -1e30f, lrun = 0.f;
  int qr = wid * 32 + lo;

  for (int hf = (n == 0) ? 1 : 0; hf < 2; ++hf) {  // n==0: half0 fully masked
    int tg = (n - 1 + hf) * 128;                   // first key token (within b)
    // stage K: LDS slot (r, dc) <- global chunk dc^(r&7)  (linear DMA dest)
#pragma unroll
    for (int p = 0; p < 4; ++p) {
      int idx = p * 256 + tid;
      int r = idx >> 3, dc = idx & 7;
      gload16(kb + (size_t)(b * 4096 + tg + r) * 64 + ((dc ^ (r & 7)) << 3),
              ks + idx * 8);
    }
    // stage V^T: LDS slot (dd, s) <- global key-chunk s^(dd&7)
#pragma unroll
    for (int p = 0; p < 4; ++p) {
      int idx = p * 256 + tid;
      int dd = idx >> 4, s = idx & 15;
      gload16(vtg + (size_t)(b * 64 + dd) * 4096 + tg + ((s ^ (dd & 7)) << 3),
              vts + idx * 8);
    }
    __syncthreads();

    // S^T = K * Q^T : A = K rows (key), B = Q (col = q)
    f32x16 S[4] = {};
#pragma unroll
    for (int mt = 0; mt < 4; ++mt) {
      int r = mt * 32 + lo;
#pragma unroll
      for (int kst = 0; kst < 4; ++kst) {
        short8 kf = *(const short8*)&ks[r * 64 + ((((kst << 1) | hi) ^ (r & 7)) << 3)];
        S[mt] = mfma32(kf, aq[kst], S[mt]);
      }
    }
    // mask + scale: key row = (reg&3)+8*(reg>>2)+4*hi+32*mt, q col = qr
#pragma unroll
    for (int mt = 0; mt < 4; ++mt)
#pragma unroll
      for (int r = 0; r < 16; ++r) {
        int kg = hf * 128 + mt * 32 + (r & 3) + ((r >> 2) << 3) + (hi << 2);
        S[mt][r] = (kg >= qr && kg <= qr + 128) ? S[mt][r] * 0.125f : -1e30f;
      }
    // online softmax: row = lane (both hi halves combined via one swap)
    float mx = -3e38f;
#pragma unroll
    for (int mt = 0; mt < 4; ++mt)
#pragma unroll
      for (int r = 0; r < 16; ++r) mx = fmaxf(mx, S[mt][r]);
    mx = fmaxf(mx, __shfl_xor(mx, 32));
    float mn = fmaxf(mrun, mx);
    float al = __expf(mrun - mn);
    mrun = mn;
    float ls = 0.f;
#pragma unroll
    for (int mt = 0; mt < 4; ++mt)
#pragma unroll
      for (int r = 0; r < 16; ++r) {
        float p = __expf(S[mt][r] - mn);
        S[mt][r] = p;
        ls += p;
      }
    ls += __shfl_xor(ls, 32);
    lrun = lrun * al + ls;
#pragma unroll
    for (int r = 0; r < 16; ++r) { O0[r] *= al; O1[r] *= al; }

    // O^T += V^T * P : pack P^T B-fragments via cvt_pk + permlane32_swap
#pragma unroll
    for (int mt = 0; mt < 4; ++mt)
#pragma unroll
      for (int h2 = 0; h2 < 2; ++h2) {
        int b0 = h2 * 8;
        unsigned pk0 = cvtpk(S[mt][b0 + 0], S[mt][b0 + 1]);
        unsigned pk1 = cvtpk(S[mt][b0 + 2], S[mt][b0 + 3]);
        unsigned pk2 = cvtpk(S[mt][b0 + 4], S[mt][b0 + 5]);
        unsigned pk3 = cvtpk(S[mt][b0 + 6], S[mt][b0 + 7]);
        asm("v_permlane32_swap_b32 %0, %1" : "+v"(pk0), "+v"(pk2));
        asm("v_permlane32_swap_b32 %0, %1" : "+v"(pk1), "+v"(pk3));
        uint4v uw; uw.x = pk0; uw.y = pk1; uw.z = pk2; uw.w = pk3;
        short8 pb = __builtin_bit_cast(short8, uw);
        int kc = mt * 4 + h2 * 2 + hi;             // key chunk 0..15
        short8 vb0 = *(const short8*)&vts[lo * 128 + ((kc ^ (lo & 7)) << 3)];
        short8 vb1 = *(const short8*)&vts[(32 + lo) * 128 + ((kc ^ (lo & 7)) << 3)];
        O0 = mfma32(vb0, pb, O0);
        O1 = mfma32(vb1, pb, O1);
      }
    __syncthreads();
  }

  // epilogue: O^T/l -> LDS transpose -> coalesced bf16 stores
  float inv = 1.f / lrun;
  float* ot = (float*)smem + wid * 2112;           // [64 d][33] per wave
#pragma unroll
  for (int r = 0; r < 16; ++r) {
    int d0 = (r & 3) + ((r >> 2) << 3) + (hi << 2);
    ot[d0 * 33 + lo]        = O0[r] * inv;
    ot[(d0 + 32) * 33 + lo] = O1[r] * inv;
  }
  __syncthreads();
  int tok = lane >> 3, dc = lane & 7;
#pragma unroll
  for (int g = 0; g < 4; ++g) {
    int q = g * 8 + tok;
    short8 o8;
#pragma unroll
    for (int jj = 0; jj < 8; ++jj)
      o8[jj] = (short)f2bf(ot[(dc * 8 + jj) * 33 + q]);
    *(short8*)&y[(size_t)(b * 4096 + n * 128 + wid * 32 + q) * 1024 + h * 64 + dc * 8] = o8;
  }
}

// ---------------- launch ----------------
extern "C" void kernel_launch(void* const* d_in, const int* in_sizes, int n_in,
                              void* d_out, int out_size, void* d_ws, size_t ws_size,
                              hipStream_t stream) {
  const float* x      = (const float*)d_in[0];
  const int*   pos    = (const int*)d_in[1];
  const float* w_attn = (const float*)d_in[2];
  const float* w_proj = (const float*)d_in[3];
  const float* qw     = (const float*)d_in[4];
  const float* kw     = (const float*)d_in[5];

  char* ws = (char*)d_ws;
  short* xb   = (short*)ws;                         // 33,554,432 B (aliased as y later)
  short* wabt = (short*)(ws + 33554432);            //  2,359,296 B
  short* wpbt = (short*)(ws + 35913728);            //  2,097,152 B
  short* qkvb = (short*)(ws + 38010880);            // 37,748,736 B
  short* qb2  = (short*)(ws + 75759616);            // 33,554,432 B
  short* kb2  = (short*)(ws + 109314048);           //  2,097,152 B
  short* vtg  = (short*)(ws + 111411200);           //  2,097,152 B (total 113.5 MB)
  short* ybuf = xb;                                 // xb dead after qkv GEMM

  hipLaunchKernelGGL(k_cvt, dim3(16384), dim3(256), 0, stream, x, xb, 4194304);
  hipLaunchKernelGGL(k_tcvt, dim3(32, 36), dim3(256), 0, stream, w_attn, wabt, 1024, 1152);
  hipLaunchKernelGGL(k_tcvt, dim3(32, 32), dim3(256), 0, stream, w_proj, wpbt, 1024, 1024);
  hipLaunchKernelGGL(k_gemm, dim3(1152), dim3(256), 0, stream, xb, wabt, (void*)qkvb,
                     16384, 1152, 1024, 1);
  hipLaunchKernelGGL(k_qk, dim3(16384), dim3(64), 0, stream, qkvb, pos, qw, kw, qb2, kb2);
  hipLaunchKernelGGL(k_vt, dim3(256), dim3(256), 0, stream, qkvb, vtg);
  hipLaunchKernelGGL(k_attn, dim3(2048), dim3(256), 0, stream, qb2, kb2, vtg, ybuf);
  hipLaunchKernelGGL(k_gemm, dim3(1024), dim3(256), 0, stream, ybuf, wpbt, d_out,
                     16384, 1024, 1024, 0);
}

// Round 3
// 207.622 us; speedup vs baseline: 1.9053x; 1.1487x over previous
//
#include <hip/hip_runtime.h>

// MQA fused layer, MI355X gfx950.
// B=4 T=4096 C=1024 H=16 D=64 W=128 NB=32.
// Pipeline: cvt(x)->bf16 | transpose-cvt weights | GEMM qkv (bf16 MFMA) |
//           RMS+RoPE q,k | V transpose | blocked sliding-window attention
//           (swapped-QK^T, per-subtile in-register online softmax) | GEMM proj.

typedef __attribute__((ext_vector_type(8))) short short8;
typedef __attribute__((ext_vector_type(4))) float f32x4;
typedef __attribute__((ext_vector_type(16))) float f32x16;
typedef __attribute__((ext_vector_type(4))) unsigned uint4v;

#define DEV static __device__ __forceinline__

DEV unsigned short f2bf(float f) {           // fp32 -> bf16 RNE
  unsigned u = __builtin_bit_cast(unsigned, f);
  u += 0x7fffu + ((u >> 16) & 1u);
  return (unsigned short)(u >> 16);
}
DEV float bf2f(unsigned short s) {
  unsigned u = ((unsigned)s) << 16;
  return __builtin_bit_cast(float, u);
}
DEV unsigned cvtpk(float a, float b) {       // {bf16(a), bf16(b)} packed
  unsigned r;
  asm("v_cvt_pk_bf16_f32 %0, %1, %2" : "=v"(r) : "v"(a), "v"(b));
  return r;
}

DEV f32x4 mfma16(short8 a, short8 b, f32x4 c) {
  return __builtin_amdgcn_mfma_f32_16x16x32_bf16(a, b, c, 0, 0, 0);
}
DEV f32x16 mfma32(short8 a, short8 b, f32x16 c) {
  return __builtin_amdgcn_mfma_f32_32x32x16_bf16(a, b, c, 0, 0, 0);
}

// async global->LDS, 16B per lane
DEV void gload16(const void* g, void* l) {
  __builtin_amdgcn_global_load_lds(
      (const __attribute__((address_space(1))) unsigned int*)(unsigned long long)g,
      (__attribute__((address_space(3))) unsigned int*)(unsigned int)(unsigned long long)l,
      16, 0, 0);
}

// ---------------- kernel: f32 -> bf16 elementwise ----------------
__global__ __launch_bounds__(256) void k_cvt(const float* __restrict__ in,
                                             short* __restrict__ out, int n4) {
  int i = blockIdx.x * 256 + threadIdx.x;
  if (i >= n4) return;
  float4 v = ((const float4*)in)[i];
  short4 o;
  o.x = (short)f2bf(v.x); o.y = (short)f2bf(v.y);
  o.z = (short)f2bf(v.z); o.w = (short)f2bf(v.w);
  ((short4*)out)[i] = o;
}

// ---------------- kernel: W (KxN f32) -> Wt (NxK bf16) ----------------
__global__ __launch_bounds__(256) void k_tcvt(const float* __restrict__ W,
                                              short* __restrict__ Wt, int K, int N) {
  __shared__ float tl[32][33];
  int tx = threadIdx.x & 31, ty = threadIdx.x >> 5;   // 32 x 8
  int k0 = blockIdx.x * 32, n0 = blockIdx.y * 32;
#pragma unroll
  for (int i = 0; i < 4; ++i)
    tl[ty + i * 8][tx] = W[(size_t)(k0 + ty + i * 8) * N + n0 + tx];
  __syncthreads();
#pragma unroll
  for (int i = 0; i < 4; ++i)
    Wt[(size_t)(n0 + ty + i * 8) * K + k0 + tx] = (short)f2bf(tl[tx][ty + i * 8]);
}

// ---------------- kernel: 128x128x32 bf16 GEMM (m97 structure) ----------------
__global__ __launch_bounds__(256) void k_gemm(const short* __restrict__ A,
                                              const short* __restrict__ Bt,
                                              void* __restrict__ Cout,
                                              int M, int N, int K, int outBf16) {
  __shared__ short As[128 * 32];
  __shared__ short Bs[128 * 32];
  int nbn = N >> 7;
  int nwg = (M >> 7) * nbn;
  int bid = blockIdx.x;
  int swz = (bid & 7) * (nwg >> 3) + (bid >> 3);   // XCD swizzle (nwg % 8 == 0)
  int bn = swz % nbn, bm = swz / nbn;
  int tid = threadIdx.x, lane = tid & 63, wid = tid >> 6;
  int wr = wid >> 1, wc = wid & 1;
  int lo = lane & 15, hi = lane >> 4;
  const short* Ab = A + (size_t)(bm * 128 + (tid >> 2)) * K + (tid & 3) * 8;
  const short* Bb = Bt + (size_t)(bn * 128 + (tid >> 2)) * K + (tid & 3) * 8;
  f32x4 acc[4][4] = {};
  for (int kt = 0; kt < K; kt += 32) {
    gload16(Ab + kt,            As + tid * 8);
    gload16(Ab + kt + 64 * K,   As + 2048 + tid * 8);
    gload16(Bb + kt,            Bs + tid * 8);
    gload16(Bb + kt + 64 * K,   Bs + 2048 + tid * 8);
    __syncthreads();
    short8 a[4], b[4];
#pragma unroll
    for (int m = 0; m < 4; ++m)
      a[m] = *(const short8*)&As[(wr * 64 + m * 16 + lo) * 32 + hi * 8];
#pragma unroll
    for (int n = 0; n < 4; ++n)
      b[n] = *(const short8*)&Bs[(wc * 64 + n * 16 + lo) * 32 + hi * 8];
#pragma unroll
    for (int m = 0; m < 4; ++m)
#pragma unroll
      for (int n = 0; n < 4; ++n)
        acc[m][n] = mfma16(a[m], b[n], acc[m][n]);
    __syncthreads();
  }
  int row0 = bm * 128 + wr * 64 + hi * 4;
  int col0 = bn * 128 + wc * 64 + lo;
  if (outBf16) {
    short* C = (short*)Cout;
#pragma unroll
    for (int m = 0; m < 4; ++m)
#pragma unroll
      for (int n = 0; n < 4; ++n)
#pragma unroll
        for (int r = 0; r < 4; ++r)
          C[(size_t)(row0 + m * 16 + r) * N + col0 + n * 16] = (short)f2bf(acc[m][n][r]);
  } else {
    float* C = (float*)Cout;
#pragma unroll
    for (int m = 0; m < 4; ++m)
#pragma unroll
      for (int n = 0; n < 4; ++n)
#pragma unroll
        for (int r = 0; r < 4; ++r)
          C[(size_t)(row0 + m * 16 + r) * N + col0 + n * 16] = acc[m][n][r];
  }
}

// ---------------- kernel: RMSNorm + RoPE for q (16 heads) and k ----------------
// 256 threads = 4 waves; each wave (64 lanes = D) handles one token
__global__ __launch_bounds__(256) void k_qk(const short* __restrict__ qkvb,
                                            const int* __restrict__ pos,
                                            const float* __restrict__ qw,
                                            const float* __restrict__ kw,
                                            short* __restrict__ qb,
                                            short* __restrict__ kb) {
  int bt = blockIdx.x * 4 + (threadIdx.x >> 6);    // b*4096 + t
  int t = bt & 4095, b = bt >> 12;
  int d = threadIdx.x & 63;                        // 0..63
  int j = d & 31;
  float invf = __expf((float)j * (-13.815510558f / 32.f));
  float sn, cs;
  sincosf((float)pos[t * 3 + (j % 3)] * invf, &sn, &cs);
  const short* base = qkvb + (size_t)bt * 1152;
  float wq = qw[d], wk = kw[d];

  auto rowproc = [&](float x, float w) -> float {
    float ss = x * x;
    ss += __shfl_xor(ss, 1);  ss += __shfl_xor(ss, 2);  ss += __shfl_xor(ss, 4);
    ss += __shfl_xor(ss, 8);  ss += __shfl_xor(ss, 16); ss += __shfl_xor(ss, 32);
    float xn = x * rsqrtf(ss * 0.015625f + 1e-6f) * w;
    float pr = __shfl_xor(xn, 32);                 // RoPE partner d +- 32
    return (d < 32) ? xn * cs - pr * sn : xn * cs + pr * sn;
  };
  {
    float x = bf2f((unsigned short)base[1024 + d]);
    kb[(size_t)bt * 64 + d] = (short)f2bf(rowproc(x, wk));
  }
#pragma unroll 4
  for (int hh = 0; hh < 16; ++hh) {
    float x = bf2f((unsigned short)base[hh * 64 + d]);
    qb[((size_t)((b * 16 + hh) * 4096 + t)) * 64 + d] = (short)f2bf(rowproc(x, wq));
  }
}

// ---------------- kernel: V slice of qkv -> vtg[b][64][4096] ----------------
__global__ __launch_bounds__(256) void k_vt(const short* __restrict__ qkvb,
                                            short* __restrict__ vtg) {
  __shared__ short ts[64][72];                     // 72: 16B-aligned rows
  int t0 = blockIdx.x * 64;
  int b = t0 >> 12, tl0 = t0 & 4095;
  int row = threadIdx.x >> 2, c4 = threadIdx.x & 3;
  const short* src = qkvb + (size_t)(t0 + row) * 1152 + 1088 + c4 * 16;
  *(short8*)&ts[row][c4 * 16]     = *(const short8*)src;
  *(short8*)&ts[row][c4 * 16 + 8] = *(const short8*)(src + 8);
  __syncthreads();
  short8 o0, o1;                                   // row = d, c4 = token group
#pragma unroll
  for (int jj = 0; jj < 8; ++jj) {
    o0[jj] = ts[c4 * 16 + jj][row];
    o1[jj] = ts[c4 * 16 + 8 + jj][row];
  }
  short* dst = vtg + (size_t)(b * 64 + row) * 4096 + tl0 + c4 * 16;
  *(short8*)dst = o0;
  *(short8*)(dst + 8) = o1;
}

// ---------------- kernel: blocked sliding-window attention (swapped QK^T) ----
// grid 2048 = (b, n, h fastest). 4 waves x 32 q-rows. Per-32-key-subtile
// online softmax keeps only one f32x16 S live -> no VGPR spill at 128-reg cap.
__global__ __launch_bounds__(256, 4) void k_attn(const short* __restrict__ qb,
                                                 const short* __restrict__ kb,
                                                 const short* __restrict__ vtg,
                                                 short* __restrict__ y) {
  __shared__ __align__(16) char smem[33792];
  short* ks  = (short*)smem;            // [128 key][64 d], chunk-XOR swizzled
  short* vts = (short*)(smem + 16384);  // [64 d][128 key], chunk-XOR swizzled
  int bid = blockIdx.x;
  int swz = (bid & 7) * 256 + (bid >> 3);          // XCD swizzle
  int h = swz & 15, n = (swz >> 4) & 31, b = swz >> 9;
  int tid = threadIdx.x, wid = tid >> 6, lane = tid & 63;
  int lo = lane & 31, hi = lane >> 5;

  // Q fragments (B-operand: col = q-row = lane&31, k-chunk = s*16 + hi*8)
  const short* qrow = qb + (size_t)((b * 16 + h) * 4096 + n * 128 + wid * 32 + lo) * 64;
  short8 aq[4];
#pragma unroll
  for (int s = 0; s < 4; ++s) aq[s] = *(const short8*)(qrow + s * 16 + hi * 8);

  f32x16 O0 = {}, O1 = {};                         // O^T: rows d / d+32, col q
  float mrun = -1e30f, lrun = 0.f;
  int qr = wid * 32 + lo;
  const float SC = 0.125f * 1.4426950408889634f;   // scale * log2(e)

  for (int hf = (n == 0) ? 1 : 0; hf < 2; ++hf) {  // n==0: half0 fully masked
    int tg = (n - 1 + hf) * 128;                   // first key token (within b)
    // stage K: LDS slot (r, dc) <- global chunk dc^(r&7)  (linear DMA dest)
#pragma unroll
    for (int p = 0; p < 4; ++p) {
      int idx = p * 256 + tid;
      int r = idx >> 3, dc = idx & 7;
      gload16(kb + (size_t)(b * 4096 + tg + r) * 64 + ((dc ^ (r & 7)) << 3),
              ks + idx * 8);
    }
    // stage V^T: LDS slot (dd, s) <- global key-chunk s^(dd&7)
#pragma unroll
    for (int p = 0; p < 4; ++p) {
      int idx = p * 256 + tid;
      int dd = idx >> 4, s = idx & 15;
      gload16(vtg + (size_t)(b * 64 + dd) * 4096 + tg + ((s ^ (dd & 7)) << 3),
              vts + idx * 8);
    }
    __syncthreads();

#pragma unroll
    for (int mt = 0; mt < 4; ++mt) {
      // S^T subtile = K(32 keys) * Q^T : one f32x16 live at a time
      f32x16 S = {};
      int r = mt * 32 + lo;
#pragma unroll
      for (int kst = 0; kst < 4; ++kst) {
        short8 kf = *(const short8*)&ks[r * 64 + ((((kst << 1) | hi) ^ (r & 7)) << 3)];
        S = mfma32(kf, aq[kst], S);
      }
      // mask + scale into log2 domain: key = 32*mt + (reg&3)+8*(reg>>2)+4*hi
#pragma unroll
      for (int rr = 0; rr < 16; ++rr) {
        int kg = hf * 128 + mt * 32 + (rr & 3) + ((rr >> 2) << 3) + (hi << 2);
        S[rr] = (kg >= qr && kg <= qr + 128) ? S[rr] * SC : -30000.f;
      }
      // online max with defer-rescale (T13): skip O-rescale if growth <= 8
      float pmax = S[0];
#pragma unroll
      for (int rr = 1; rr < 16; ++rr) pmax = fmaxf(pmax, S[rr]);
      pmax = fmaxf(pmax, __shfl_xor(pmax, 32));
      if (!__all(pmax - mrun <= 8.f)) {
        float mn = fmaxf(mrun, pmax);
        float al = exp2f(mrun - mn);
        lrun *= al; mrun = mn;
#pragma unroll
        for (int rr = 0; rr < 16; ++rr) { O0[rr] *= al; O1[rr] *= al; }
      }
      float ls = 0.f;
#pragma unroll
      for (int rr = 0; rr < 16; ++rr) { S[rr] = exp2f(S[rr] - mrun); ls += S[rr]; }
      ls += __shfl_xor(ls, 32);
      lrun += ls;
      // O^T += V^T * P : pack P^T B-fragments via cvt_pk + permlane32_swap
#pragma unroll
      for (int h2 = 0; h2 < 2; ++h2) {
        int b0 = h2 * 8;
        unsigned pk0 = cvtpk(S[b0 + 0], S[b0 + 1]);
        unsigned pk1 = cvtpk(S[b0 + 2], S[b0 + 3]);
        unsigned pk2 = cvtpk(S[b0 + 4], S[b0 + 5]);
        unsigned pk3 = cvtpk(S[b0 + 6], S[b0 + 7]);
        asm("v_permlane32_swap_b32 %0, %1" : "+v"(pk0), "+v"(pk2));
        asm("v_permlane32_swap_b32 %0, %1" : "+v"(pk1), "+v"(pk3));
        uint4v uw; uw.x = pk0; uw.y = pk1; uw.z = pk2; uw.w = pk3;
        short8 pb = __builtin_bit_cast(short8, uw);
        int kc = mt * 4 + h2 * 2 + hi;             // key chunk 0..15
        short8 vb0 = *(const short8*)&vts[lo * 128 + ((kc ^ (lo & 7)) << 3)];
        short8 vb1 = *(const short8*)&vts[(32 + lo) * 128 + ((kc ^ (lo & 7)) << 3)];
        O0 = mfma32(vb0, pb, O0);
        O1 = mfma32(vb1, pb, O1);
      }
    }
    __syncthreads();
  }

  // epilogue: O^T/l -> LDS transpose -> coalesced bf16 stores
  float inv = 1.f / lrun;
  float* ot = (float*)smem + wid * 2112;           // [64 d][33] per wave
#pragma unroll
  for (int r = 0; r < 16; ++r) {
    int d0 = (r & 3) + ((r >> 2) << 3) + (hi << 2);
    ot[d0 * 33 + lo]        = O0[r] * inv;
    ot[(d0 + 32) * 33 + lo] = O1[r] * inv;
  }
  __syncthreads();
  int tok = lane >> 3, dc = lane & 7;
#pragma unroll
  for (int g = 0; g < 4; ++g) {
    int q = g * 8 + tok;
    short8 o8;
#pragma unroll
    for (int jj = 0; jj < 8; ++jj)
      o8[jj] = (short)f2bf(ot[(dc * 8 + jj) * 33 + q]);
    *(short8*)&y[(size_t)(b * 4096 + n * 128 + wid * 32 + q) * 1024 + h * 64 + dc * 8] = o8;
  }
}

// ---------------- launch ----------------
extern "C" void kernel_launch(void* const* d_in, const int* in_sizes, int n_in,
                              void* d_out, int out_size, void* d_ws, size_t ws_size,
                              hipStream_t stream) {
  const float* x      = (const float*)d_in[0];
  const int*   pos    = (const int*)d_in[1];
  const float* w_attn = (const float*)d_in[2];
  const float* w_proj = (const float*)d_in[3];
  const float* qw     = (const float*)d_in[4];
  const float* kw     = (const float*)d_in[5];

  char* ws = (char*)d_ws;
  short* xb   = (short*)ws;                         // 33,554,432 B (aliased as y later)
  short* wabt = (short*)(ws + 33554432);            //  2,359,296 B
  short* wpbt = (short*)(ws + 35913728);            //  2,097,152 B
  short* qkvb = (short*)(ws + 38010880);            // 37,748,736 B
  short* qb2  = (short*)(ws + 75759616);            // 33,554,432 B
  short* kb2  = (short*)(ws + 109314048);           //  2,097,152 B
  short* vtg  = (short*)(ws + 111411200);           //  2,097,152 B (total 113.5 MB)
  short* ybuf = xb;                                 // xb dead after qkv GEMM

  hipLaunchKernelGGL(k_cvt, dim3(16384), dim3(256), 0, stream, x, xb, 4194304);
  hipLaunchKernelGGL(k_tcvt, dim3(32, 36), dim3(256), 0, stream, w_attn, wabt, 1024, 1152);
  hipLaunchKernelGGL(k_tcvt, dim3(32, 32), dim3(256), 0, stream, w_proj, wpbt, 1024, 1024);
  hipLaunchKernelGGL(k_gemm, dim3(1152), dim3(256), 0, stream, xb, wabt, (void*)qkvb,
                     16384, 1152, 1024, 1);
  hipLaunchKernelGGL(k_qk, dim3(4096), dim3(256), 0, stream, qkvb, pos, qw, kw, qb2, kb2);
  hipLaunchKernelGGL(k_vt, dim3(256), dim3(256), 0, stream, qkvb, vtg);
  hipLaunchKernelGGL(k_attn, dim3(2048), dim3(256), 0, stream, qb2, kb2, vtg, ybuf);
  hipLaunchKernelGGL(k_gemm, dim3(1024), dim3(256), 0, stream, ybuf, wpbt, d_out,
                     16384, 1024, 1024, 0);
}

// Round 4
// 193.001 us; speedup vs baseline: 2.0497x; 1.0758x over previous
//
#include <hip/hip_runtime.h>

// MQA fused layer, MI355X gfx950.
// B=4 T=4096 C=1024 H=16 D=64 W=128 NB=32.
// Pipeline: cvt(x)->bf16 | transpose-cvt weights | GEMM qkv (256^2 8-phase) |
//           RMS+RoPE q,k | V transpose | blocked sliding-window attention
//           (swapped-QK^T, in-register online softmax) | GEMM proj (256^2).

typedef __attribute__((ext_vector_type(8))) short short8;
typedef __attribute__((ext_vector_type(4))) float f32x4;
typedef __attribute__((ext_vector_type(16))) float f32x16;
typedef __attribute__((ext_vector_type(4))) unsigned uint4v;

#define DEV static __device__ __forceinline__

DEV unsigned short f2bf(float f) {           // fp32 -> bf16 RNE
  unsigned u = __builtin_bit_cast(unsigned, f);
  u += 0x7fffu + ((u >> 16) & 1u);
  return (unsigned short)(u >> 16);
}
DEV float bf2f(unsigned short s) {
  unsigned u = ((unsigned)s) << 16;
  return __builtin_bit_cast(float, u);
}
DEV unsigned cvtpk(float a, float b) {       // {bf16(a), bf16(b)} packed
  unsigned r;
  asm("v_cvt_pk_bf16_f32 %0, %1, %2" : "=v"(r) : "v"(a), "v"(b));
  return r;
}

DEV f32x4 mfma16(short8 a, short8 b, f32x4 c) {
  return __builtin_amdgcn_mfma_f32_16x16x32_bf16(a, b, c, 0, 0, 0);
}
DEV f32x16 mfma32(short8 a, short8 b, f32x16 c) {
  return __builtin_amdgcn_mfma_f32_32x32x16_bf16(a, b, c, 0, 0, 0);
}

// async global->LDS, 16B per lane
DEV void gload16(const void* g, void* l) {
  __builtin_amdgcn_global_load_lds(
      (const __attribute__((address_space(1))) unsigned int*)(unsigned long long)g,
      (__attribute__((address_space(3))) unsigned int*)(unsigned int)(unsigned long long)l,
      16, 0, 0);
}

#define BARRIER __builtin_amdgcn_s_barrier()
#define LGKM0 do { asm volatile("s_waitcnt lgkmcnt(0)" ::: "memory"); \
                   __builtin_amdgcn_sched_barrier(0); } while (0)
#define VMCNT4 do { asm volatile("s_waitcnt vmcnt(4)" ::: "memory"); \
                    __builtin_amdgcn_sched_barrier(0); } while (0)

// ---------------- kernel: f32 -> bf16 elementwise ----------------
__global__ __launch_bounds__(256) void k_cvt(const float* __restrict__ in,
                                             short* __restrict__ out, int n4) {
  int i = blockIdx.x * 256 + threadIdx.x;
  if (i >= n4) return;
  float4 v = ((const float4*)in)[i];
  short4 o;
  o.x = (short)f2bf(v.x); o.y = (short)f2bf(v.y);
  o.z = (short)f2bf(v.z); o.w = (short)f2bf(v.w);
  ((short4*)out)[i] = o;
}

// ---------------- kernel: W (KxN f32) -> Wt (NxK bf16) ----------------
__global__ __launch_bounds__(256) void k_tcvt(const float* __restrict__ W,
                                              short* __restrict__ Wt, int K, int N) {
  __shared__ float tl[32][33];
  int tx = threadIdx.x & 31, ty = threadIdx.x >> 5;   // 32 x 8
  int k0 = blockIdx.x * 32, n0 = blockIdx.y * 32;
#pragma unroll
  for (int i = 0; i < 4; ++i)
    tl[ty + i * 8][tx] = W[(size_t)(k0 + ty + i * 8) * N + n0 + tx];
  __syncthreads();
#pragma unroll
  for (int i = 0; i < 4; ++i)
    Wt[(size_t)(n0 + ty + i * 8) * K + k0 + tx] = (short)f2bf(tl[tx][ty + i * 8]);
}

// ---------------- kernel: 256x256x64 bf16 GEMM, 8-phase schedule ------------
// A: MxK row-major bf16. Bt: NxK row-major bf16. C: MxN (bf16 or f32).
// 8 waves (2M x 4N), per-wave C = 128x64. LDS 128 KiB: [dbuf][A/B][half][128][64],
// chunk-XOR swizzled (chunk' = chunk ^ (row&7)), staged via global_load_lds with
// pre-swizzled global source. Per K-tile: 4 phases; counted vmcnt(4) per tile.
__global__ __launch_bounds__(512, 2) void k_gemm256(const short* __restrict__ A,
                                                    const short* __restrict__ Bt,
                                                    void* __restrict__ Cout,
                                                    int M, int N, int K, int outBf16) {
  __shared__ short sm[65536];                       // 128 KiB
  int nbn = N >> 8;
  int nwg = (M >> 8) * nbn;
  int bid = blockIdx.x;
  int swz = (bid & 7) * (nwg >> 3) + (bid >> 3);    // XCD swizzle (nwg % 8 == 0)
  int bm = swz / nbn, bn = swz % nbn;
  int tid = threadIdx.x, wid = tid >> 6, lane = tid & 63;
  int wm = wid >> 2, wn = wid & 3;
  int lo = lane & 15, hi = lane >> 4;
  int NT = K >> 6;                                  // # K-tiles (BK=64)

  // staging: thread covers (row r0, chunk dc) and (r0+64, dc) of a 128x8-chunk half
  int r0 = tid >> 3, dc = tid & 7;
  int sc = dc ^ (r0 & 7);                           // pre-swizzled source chunk
  const short* aS0 = A  + (size_t)(bm * 256 + r0) * K + sc * 8;        // half 0
  const short* bS0 = Bt + (size_t)(bn * 256 + r0) * K + sc * 8;
  size_t hstep = (size_t)128 * K;                   // half 1 = +128 rows

  // stage one half-tile: mat 0=A 1=B, half h, dbuf d, K-tile jt
  auto stage = [&](int jt, int mat, int h, int d) {
    const short* s = (mat ? bS0 : aS0) + (size_t)h * hstep + jt * 64;
    short* l = sm + d * 32768 + mat * 16384 + h * 8192;
    gload16(s,                     l + tid * 8);
    gload16(s + (size_t)64 * K,    l + 4096 + tid * 8);
  };

  // ds-read fragment offsets (element): row lo, chunk (kk*4+hi)^(lo&7)
  int aRd[2];
#pragma unroll
  for (int kk = 0; kk < 2; ++kk)
    aRd[kk] = lo * 64 + (((kk << 2) | hi) ^ (lo & 7)) * 8;

  short8 Afr[8][2];                                 // 8 Mfrag x 2 kk
  short8 Bfr[2][2];                                 // 2 live Nfrag x 2 kk
  f32x4 acc[8][4] = {};

  auto rdA = [&](int d, int m0) {
    int base = d * 32768 + wm * 8192;
#pragma unroll
    for (int m = 0; m < 4; ++m)
#pragma unroll
      for (int kk = 0; kk < 2; ++kk)
        Afr[m0 + m][kk] = *(const short8*)&sm[base + (m0 + m) * 1024 + aRd[kk]];
  };
  auto rdB = [&](int d, int n0) {
    int base = d * 32768 + 16384 + (wn >> 1) * 8192 + (wn & 1) * 4096;
#pragma unroll
    for (int nf = 0; nf < 2; ++nf)
#pragma unroll
      for (int kk = 0; kk < 2; ++kk)
        Bfr[nf][kk] = *(const short8*)&sm[base + (n0 + nf) * 1024 + aRd[kk]];
  };
  auto quad = [&](int m0, int n0) {                 // 16 MFMA: 4 Mfrag x 2 Nfrag x 2 kk
    __builtin_amdgcn_s_setprio(1);
#pragma unroll
    for (int m = 0; m < 4; ++m)
#pragma unroll
      for (int j = 0; j < 2; ++j)
#pragma unroll
        for (int kk = 0; kk < 2; ++kk)
          acc[m0 + m][n0 + j] = mfma16(Afr[m0 + m][kk], Bfr[j][kk], acc[m0 + m][n0 + j]);
    __builtin_amdgcn_s_setprio(0);
  };

  // prologue: tile0 all 4 halves (dbuf0), tile1 A0,B0 (dbuf1); keep 4 in flight
  stage(0, 0, 0, 0); stage(0, 1, 0, 0); stage(0, 0, 1, 0); stage(0, 1, 1, 0);
  if (NT > 1) { stage(1, 0, 0, 1); stage(1, 1, 0, 1); }
  VMCNT4;
  BARRIER;

#pragma unroll 2
  for (int jt = 0; jt < NT; ++jt) {
    int d = jt & 1;
    // ph0: read A M0-3 + B N0-1; stage (jt+1, A1)
    rdA(d, 0); rdB(d, 0);
    if (jt + 1 < NT) stage(jt + 1, 0, 1, d ^ 1);
    BARRIER; LGKM0;
    quad(0, 0);
    BARRIER;
    // ph1: read A M4-7; stage (jt+1, B1)
    rdA(d, 4);
    if (jt + 1 < NT) stage(jt + 1, 1, 1, d ^ 1);
    BARRIER; LGKM0;
    quad(4, 0);
    BARRIER;
    // ph2: read B N2-3; stage (jt+2, A0)
    rdB(d, 2);
    if (jt + 2 < NT) stage(jt + 2, 0, 0, d);
    BARRIER; LGKM0;
    quad(0, 2);
    BARRIER;
    // ph3: stage (jt+2, B0); counted vmcnt (never 0 in-loop)
    if (jt + 2 < NT) stage(jt + 2, 1, 0, d);
    VMCNT4;
    BARRIER;
    quad(4, 2);
    BARRIER;
  }

  // epilogue: C layout col = lane&15, row = (lane>>4)*4 + reg
  int row0 = bm * 256 + wm * 128 + hi * 4;
  int col0 = bn * 256 + wn * 64 + lo;
  if (outBf16) {
    short* C = (short*)Cout;
#pragma unroll
    for (int m = 0; m < 8; ++m)
#pragma unroll
      for (int nf = 0; nf < 4; ++nf)
#pragma unroll
        for (int r = 0; r < 4; ++r)
          C[(size_t)(row0 + m * 16 + r) * N + col0 + nf * 16] = (short)f2bf(acc[m][nf][r]);
  } else {
    float* C = (float*)Cout;
#pragma unroll
    for (int m = 0; m < 8; ++m)
#pragma unroll
      for (int nf = 0; nf < 4; ++nf)
#pragma unroll
        for (int r = 0; r < 4; ++r)
          C[(size_t)(row0 + m * 16 + r) * N + col0 + nf * 16] = acc[m][nf][r];
  }
}

// ---------------- kernel: RMSNorm + RoPE for q (16 heads) and k ----------------
// 256 threads = 4 waves; each wave (64 lanes = D) handles one token
__global__ __launch_bounds__(256) void k_qk(const short* __restrict__ qkvb,
                                            const int* __restrict__ pos,
                                            const float* __restrict__ qw,
                                            const float* __restrict__ kw,
                                            short* __restrict__ qb,
                                            short* __restrict__ kb) {
  int bt = blockIdx.x * 4 + (threadIdx.x >> 6);    // b*4096 + t
  int t = bt & 4095, b = bt >> 12;
  int d = threadIdx.x & 63;                        // 0..63
  int j = d & 31;
  float invf = __expf((float)j * (-13.815510558f / 32.f));
  float sn, cs;
  sincosf((float)pos[t * 3 + (j % 3)] * invf, &sn, &cs);
  const short* base = qkvb + (size_t)bt * 1280;
  float wq = qw[d], wk = kw[d];

  auto rowproc = [&](float x, float w) -> float {
    float ss = x * x;
    ss += __shfl_xor(ss, 1);  ss += __shfl_xor(ss, 2);  ss += __shfl_xor(ss, 4);
    ss += __shfl_xor(ss, 8);  ss += __shfl_xor(ss, 16); ss += __shfl_xor(ss, 32);
    float xn = x * rsqrtf(ss * 0.015625f + 1e-6f) * w;
    float pr = __shfl_xor(xn, 32);                 // RoPE partner d +- 32
    return (d < 32) ? xn * cs - pr * sn : xn * cs + pr * sn;
  };
  {
    float x = bf2f((unsigned short)base[1024 + d]);
    kb[(size_t)bt * 64 + d] = (short)f2bf(rowproc(x, wk));
  }
#pragma unroll 4
  for (int hh = 0; hh < 16; ++hh) {
    float x = bf2f((unsigned short)base[hh * 64 + d]);
    qb[((size_t)((b * 16 + hh) * 4096 + t)) * 64 + d] = (short)f2bf(rowproc(x, wq));
  }
}

// ---------------- kernel: V slice of qkv -> vtg[b][64][4096] ----------------
__global__ __launch_bounds__(256) void k_vt(const short* __restrict__ qkvb,
                                            short* __restrict__ vtg) {
  __shared__ short ts[64][72];                     // 72: 16B-aligned rows
  int t0 = blockIdx.x * 64;
  int b = t0 >> 12, tl0 = t0 & 4095;
  int row = threadIdx.x >> 2, c4 = threadIdx.x & 3;
  const short* src = qkvb + (size_t)(t0 + row) * 1280 + 1088 + c4 * 16;
  *(short8*)&ts[row][c4 * 16]     = *(const short8*)src;
  *(short8*)&ts[row][c4 * 16 + 8] = *(const short8*)(src + 8);
  __syncthreads();
  short8 o0, o1;                                   // row = d, c4 = token group
#pragma unroll
  for (int jj = 0; jj < 8; ++jj) {
    o0[jj] = ts[c4 * 16 + jj][row];
    o1[jj] = ts[c4 * 16 + 8 + jj][row];
  }
  short* dst = vtg + (size_t)(b * 64 + row) * 4096 + tl0 + c4 * 16;
  *(short8*)dst = o0;
  *(short8*)(dst + 8) = o1;
}

// ---------------- kernel: blocked sliding-window attention (swapped QK^T) ----
// grid 2048 = (b, n, h fastest). 4 waves x 32 q-rows. Per-32-key-subtile
// online softmax keeps only one f32x16 S live -> no VGPR spill at 128-reg cap.
__global__ __launch_bounds__(256, 4) void k_attn(const short* __restrict__ qb,
                                                 const short* __restrict__ kb,
                                                 const short* __restrict__ vtg,
                                                 short* __restrict__ y) {
  __shared__ __align__(16) char smem[33792];
  short* ks  = (short*)smem;            // [128 key][64 d], chunk-XOR swizzled
  short* vts = (short*)(smem + 16384);  // [64 d][128 key], chunk-XOR swizzled
  int bid = blockIdx.x;
  int swz = (bid & 7) * 256 + (bid >> 3);          // XCD swizzle
  int h = swz & 15, n = (swz >> 4) & 31, b = swz >> 9;
  int tid = threadIdx.x, wid = tid >> 6, lane = tid & 63;
  int lo = lane & 31, hi = lane >> 5;

  // Q fragments (B-operand: col = q-row = lane&31, k-chunk = s*16 + hi*8)
  const short* qrow = qb + (size_t)((b * 16 + h) * 4096 + n * 128 + wid * 32 + lo) * 64;
  short8 aq[4];
#pragma unroll
  for (int s = 0; s < 4; ++s) aq[s] = *(const short8*)(qrow + s * 16 + hi * 8);

  f32x16 O0 = {}, O1 = {};                         // O^T: rows d / d+32, col q
  float mrun = -1e30f, lrun = 0.f;
  int qr = wid * 32 + lo;
  const float SC = 0.125f * 1.4426950408889634f;   // scale * log2(e)

  for (int hf = (n == 0) ? 1 : 0; hf < 2; ++hf) {  // n==0: half0 fully masked
    int tg = (n - 1 + hf) * 128;                   // first key token (within b)
    // stage K: LDS slot (r, dc) <- global chunk dc^(r&7)  (linear DMA dest)
#pragma unroll
    for (int p = 0; p < 4; ++p) {
      int idx = p * 256 + tid;
      int r = idx >> 3, dc = idx & 7;
      gload16(kb + (size_t)(b * 4096 + tg + r) * 64 + ((dc ^ (r & 7)) << 3),
              ks + idx * 8);
    }
    // stage V^T: LDS slot (dd, s) <- global key-chunk s^(dd&7)
#pragma unroll
    for (int p = 0; p < 4; ++p) {
      int idx = p * 256 + tid;
      int dd = idx >> 4, s = idx & 15;
      gload16(vtg + (size_t)(b * 64 + dd) * 4096 + tg + ((s ^ (dd & 7)) << 3),
              vts + idx * 8);
    }
    __syncthreads();

#pragma unroll
    for (int mt = 0; mt < 4; ++mt) {
      // S^T subtile = K(32 keys) * Q^T : one f32x16 live at a time
      f32x16 S = {};
      int r = mt * 32 + lo;
#pragma unroll
      for (int kst = 0; kst < 4; ++kst) {
        short8 kf = *(const short8*)&ks[r * 64 + ((((kst << 1) | hi) ^ (r & 7)) << 3)];
        S = mfma32(kf, aq[kst], S);
      }
      // mask + scale into log2 domain: key = 32*mt + (reg&3)+8*(reg>>2)+4*hi
#pragma unroll
      for (int rr = 0; rr < 16; ++rr) {
        int kg = hf * 128 + mt * 32 + (rr & 3) + ((rr >> 2) << 3) + (hi << 2);
        S[rr] = (kg >= qr && kg <= qr + 128) ? S[rr] * SC : -30000.f;
      }
      // online max with defer-rescale (T13): skip O-rescale if growth <= 8
      float pmax = S[0];
#pragma unroll
      for (int rr = 1; rr < 16; ++rr) pmax = fmaxf(pmax, S[rr]);
      pmax = fmaxf(pmax, __shfl_xor(pmax, 32));
      if (!__all(pmax - mrun <= 8.f)) {
        float mn = fmaxf(mrun, pmax);
        float al = exp2f(mrun - mn);
        lrun *= al; mrun = mn;
#pragma unroll
        for (int rr = 0; rr < 16; ++rr) { O0[rr] *= al; O1[rr] *= al; }
      }
      float ls = 0.f;
#pragma unroll
      for (int rr = 0; rr < 16; ++rr) { S[rr] = exp2f(S[rr] - mrun); ls += S[rr]; }
      ls += __shfl_xor(ls, 32);
      lrun += ls;
      // O^T += V^T * P : pack P^T B-fragments via cvt_pk + permlane32_swap
#pragma unroll
      for (int h2 = 0; h2 < 2; ++h2) {
        int b0 = h2 * 8;
        unsigned pk0 = cvtpk(S[b0 + 0], S[b0 + 1]);
        unsigned pk1 = cvtpk(S[b0 + 2], S[b0 + 3]);
        unsigned pk2 = cvtpk(S[b0 + 4], S[b0 + 5]);
        unsigned pk3 = cvtpk(S[b0 + 6], S[b0 + 7]);
        asm("v_permlane32_swap_b32 %0, %1" : "+v"(pk0), "+v"(pk2));
        asm("v_permlane32_swap_b32 %0, %1" : "+v"(pk1), "+v"(pk3));
        uint4v uw; uw.x = pk0; uw.y = pk1; uw.z = pk2; uw.w = pk3;
        short8 pb = __builtin_bit_cast(short8, uw);
        int kc = mt * 4 + h2 * 2 + hi;             // key chunk 0..15
        short8 vb0 = *(const short8*)&vts[lo * 128 + ((kc ^ (lo & 7)) << 3)];
        short8 vb1 = *(const short8*)&vts[(32 + lo) * 128 + ((kc ^ (lo & 7)) << 3)];
        O0 = mfma32(vb0, pb, O0);
        O1 = mfma32(vb1, pb, O1);
      }
    }
    __syncthreads();
  }

  // epilogue: O^T/l -> LDS transpose -> coalesced bf16 stores
  float inv = 1.f / lrun;
  float* ot = (float*)smem + wid * 2112;           // [64 d][33] per wave
#pragma unroll
  for (int r = 0; r < 16; ++r) {
    int d0 = (r & 3) + ((r >> 2) << 3) + (hi << 2);
    ot[d0 * 33 + lo]        = O0[r] * inv;
    ot[(d0 + 32) * 33 + lo] = O1[r] * inv;
  }
  __syncthreads();
  int tok = lane >> 3, dc = lane & 7;
#pragma unroll
  for (int g = 0; g < 4; ++g) {
    int q = g * 8 + tok;
    short8 o8;
#pragma unroll
    for (int jj = 0; jj < 8; ++jj)
      o8[jj] = (short)f2bf(ot[(dc * 8 + jj) * 33 + q]);
    *(short8*)&y[(size_t)(b * 4096 + n * 128 + wid * 32 + q) * 1024 + h * 64 + dc * 8] = o8;
  }
}

// ---------------- launch ----------------
extern "C" void kernel_launch(void* const* d_in, const int* in_sizes, int n_in,
                              void* d_out, int out_size, void* d_ws, size_t ws_size,
                              hipStream_t stream) {
  const float* x      = (const float*)d_in[0];
  const int*   pos    = (const int*)d_in[1];
  const float* w_attn = (const float*)d_in[2];
  const float* w_proj = (const float*)d_in[3];
  const float* qw     = (const float*)d_in[4];
  const float* kw     = (const float*)d_in[5];

  char* ws = (char*)d_ws;
  short* xb   = (short*)ws;                         // 33,554,432 B (aliased as y later)
  short* wabt = (short*)(ws + 33554432);            //  2,621,440 B (1280 x 1024)
  short* wpbt = (short*)(ws + 36175872);            //  2,097,152 B
  short* qkvb = (short*)(ws + 38273024);            // 41,943,040 B (16384 x 1280)
  short* qb2  = (short*)(ws + 80216064);            // 33,554,432 B
  short* kb2  = (short*)(ws + 113770496);           //  2,097,152 B
  short* vtg  = (short*)(ws + 115867648);           //  2,097,152 B (total 112.5 MiB)
  short* ybuf = xb;                                 // xb dead after qkv GEMM

  hipLaunchKernelGGL(k_cvt, dim3(16384), dim3(256), 0, stream, x, xb, 4194304);
  hipLaunchKernelGGL(k_tcvt, dim3(32, 36), dim3(256), 0, stream, w_attn, wabt, 1024, 1152);
  hipLaunchKernelGGL(k_tcvt, dim3(32, 32), dim3(256), 0, stream, w_proj, wpbt, 1024, 1024);
  hipLaunchKernelGGL(k_gemm256, dim3(320), dim3(512), 0, stream, xb, wabt, (void*)qkvb,
                     16384, 1280, 1024, 1);
  hipLaunchKernelGGL(k_qk, dim3(4096), dim3(256), 0, stream, qkvb, pos, qw, kw, qb2, kb2);
  hipLaunchKernelGGL(k_vt, dim3(256), dim3(256), 0, stream, qkvb, vtg);
  hipLaunchKernelGGL(k_attn, dim3(2048), dim3(256), 0, stream, qb2, kb2, vtg, ybuf);
  hipLaunchKernelGGL(k_gemm256, dim3(256), dim3(512), 0, stream, ybuf, wpbt, d_out,
                     16384, 1024, 1024, 0);
}

// Round 5
// 190.901 us; speedup vs baseline: 2.0722x; 1.0110x over previous
//
#include <hip/hip_runtime.h>

// MQA fused layer, MI355X gfx950.
// B=4 T=4096 C=1024 H=16 D=64 W=128 NB=32.
// Pipeline: cvt(x)->bf16 | transpose-cvt weights | GEMM qkv (256^2 8-phase) |
//           RMS+RoPE q,k | V transpose | blocked sliding-window attention
//           (swapped-QK^T, in-register online softmax) | GEMM proj (256^2).

typedef __attribute__((ext_vector_type(8))) short short8;
typedef __attribute__((ext_vector_type(4))) float f32x4;
typedef __attribute__((ext_vector_type(16))) float f32x16;
typedef __attribute__((ext_vector_type(4))) unsigned uint4v;

#define DEV static __device__ __forceinline__

DEV unsigned short f2bf(float f) {           // fp32 -> bf16 RNE
  unsigned u = __builtin_bit_cast(unsigned, f);
  u += 0x7fffu + ((u >> 16) & 1u);
  return (unsigned short)(u >> 16);
}
DEV float bf2f(unsigned short s) {
  unsigned u = ((unsigned)s) << 16;
  return __builtin_bit_cast(float, u);
}
DEV unsigned cvtpk(float a, float b) {       // {bf16(a), bf16(b)} packed
  unsigned r;
  asm("v_cvt_pk_bf16_f32 %0, %1, %2" : "=v"(r) : "v"(a), "v"(b));
  return r;
}

DEV f32x4 mfma16(short8 a, short8 b, f32x4 c) {
  return __builtin_amdgcn_mfma_f32_16x16x32_bf16(a, b, c, 0, 0, 0);
}
DEV f32x16 mfma32(short8 a, short8 b, f32x16 c) {
  return __builtin_amdgcn_mfma_f32_32x32x16_bf16(a, b, c, 0, 0, 0);
}

// async global->LDS, 16B per lane
DEV void gload16(const void* g, void* l) {
  __builtin_amdgcn_global_load_lds(
      (const __attribute__((address_space(1))) unsigned int*)(unsigned long long)g,
      (__attribute__((address_space(3))) unsigned int*)(unsigned int)(unsigned long long)l,
      16, 0, 0);
}

#define BARRIER __builtin_amdgcn_s_barrier()
// NOTE: no sched_barrier(0) here — m141: order-pinning defeats the compiler's
// scheduler (510 TF). "memory" clobber alone provides the needed ordering:
// loads can't sink below the wait, and the wait drains them.
#define LGKM0  asm volatile("s_waitcnt lgkmcnt(0)" ::: "memory")
#define VMCNT4 asm volatile("s_waitcnt vmcnt(4)" ::: "memory")

// ---------------- kernel: f32 -> bf16 elementwise ----------------
__global__ __launch_bounds__(256) void k_cvt(const float* __restrict__ in,
                                             short* __restrict__ out, int n4) {
  int i = blockIdx.x * 256 + threadIdx.x;
  if (i >= n4) return;
  float4 v = ((const float4*)in)[i];
  short4 o;
  o.x = (short)f2bf(v.x); o.y = (short)f2bf(v.y);
  o.z = (short)f2bf(v.z); o.w = (short)f2bf(v.w);
  ((short4*)out)[i] = o;
}

// ---------------- kernel: W (KxN f32) -> Wt (NxK bf16) ----------------
__global__ __launch_bounds__(256) void k_tcvt(const float* __restrict__ W,
                                              short* __restrict__ Wt, int K, int N) {
  __shared__ float tl[32][33];
  int tx = threadIdx.x & 31, ty = threadIdx.x >> 5;   // 32 x 8
  int k0 = blockIdx.x * 32, n0 = blockIdx.y * 32;
#pragma unroll
  for (int i = 0; i < 4; ++i)
    tl[ty + i * 8][tx] = W[(size_t)(k0 + ty + i * 8) * N + n0 + tx];
  __syncthreads();
#pragma unroll
  for (int i = 0; i < 4; ++i)
    Wt[(size_t)(n0 + ty + i * 8) * K + k0 + tx] = (short)f2bf(tl[tx][ty + i * 8]);
}

// ---------------- kernel: 256x256x64 bf16 GEMM, 8-phase schedule ------------
// A: MxK row-major bf16. Bt: NxK row-major bf16. C: MxN (bf16 or f32).
// 8 waves (2M x 4N), per-wave C = 128x64. LDS 128 KiB: [dbuf][A/B][half][128][64],
// chunk-XOR swizzled (chunk' = chunk ^ (row&7)), staged via global_load_lds with
// pre-swizzled global source. Per K-tile: 4 phases; counted vmcnt(4) per tile.
__global__ __launch_bounds__(512, 2) void k_gemm256(const short* __restrict__ A,
                                                    const short* __restrict__ Bt,
                                                    void* __restrict__ Cout,
                                                    int M, int N, int K, int outBf16) {
  __shared__ short sm[65536];                       // 128 KiB
  int nbn = N >> 8;
  int nwg = (M >> 8) * nbn;
  int bid = blockIdx.x;
  int swz = (bid & 7) * (nwg >> 3) + (bid >> 3);    // XCD swizzle (nwg % 8 == 0)
  int bm = swz / nbn, bn = swz % nbn;
  int tid = threadIdx.x, wid = tid >> 6, lane = tid & 63;
  int wm = wid >> 2, wn = wid & 3;
  int lo = lane & 15, hi = lane >> 4;
  int NT = K >> 6;                                  // # K-tiles (BK=64)

  // staging: thread covers (row r0, chunk dc) and (r0+64, dc) of a 128x8-chunk half
  int r0 = tid >> 3, dc = tid & 7;
  int sc = dc ^ (r0 & 7);                           // pre-swizzled source chunk
  const short* aS0 = A  + (size_t)(bm * 256 + r0) * K + sc * 8;        // half 0
  const short* bS0 = Bt + (size_t)(bn * 256 + r0) * K + sc * 8;
  size_t hstep = (size_t)128 * K;                   // half 1 = +128 rows

  // stage one half-tile: mat 0=A 1=B, half h, dbuf d, K-tile jt
  auto stage = [&](int jt, int mat, int h, int d) {
    const short* s = (mat ? bS0 : aS0) + (size_t)h * hstep + jt * 64;
    short* l = sm + d * 32768 + mat * 16384 + h * 8192;
    gload16(s,                     l + tid * 8);
    gload16(s + (size_t)64 * K,    l + 4096 + tid * 8);
  };

  // ds-read fragment offsets (element): row lo, chunk (kk*4+hi)^(lo&7)
  int aRd[2];
#pragma unroll
  for (int kk = 0; kk < 2; ++kk)
    aRd[kk] = lo * 64 + (((kk << 2) | hi) ^ (lo & 7)) * 8;

  short8 Afr[8][2];                                 // 8 Mfrag x 2 kk
  short8 Bfr[2][2];                                 // 2 live Nfrag x 2 kk
  f32x4 acc[8][4] = {};

  auto rdA = [&](int d, int m0) {
    int base = d * 32768 + wm * 8192;
#pragma unroll
    for (int m = 0; m < 4; ++m)
#pragma unroll
      for (int kk = 0; kk < 2; ++kk)
        Afr[m0 + m][kk] = *(const short8*)&sm[base + (m0 + m) * 1024 + aRd[kk]];
  };
  auto rdB = [&](int d, int n0) {
    int base = d * 32768 + 16384 + (wn >> 1) * 8192 + (wn & 1) * 4096;
#pragma unroll
    for (int nf = 0; nf < 2; ++nf)
#pragma unroll
      for (int kk = 0; kk < 2; ++kk)
        Bfr[nf][kk] = *(const short8*)&sm[base + (n0 + nf) * 1024 + aRd[kk]];
  };
  auto quad = [&](int m0, int n0) {                 // 16 MFMA: 4 Mfrag x 2 Nfrag x 2 kk
    __builtin_amdgcn_s_setprio(1);
#pragma unroll
    for (int m = 0; m < 4; ++m)
#pragma unroll
      for (int j = 0; j < 2; ++j)
#pragma unroll
        for (int kk = 0; kk < 2; ++kk)
          acc[m0 + m][n0 + j] = mfma16(Afr[m0 + m][kk], Bfr[j][kk], acc[m0 + m][n0 + j]);
    __builtin_amdgcn_s_setprio(0);
  };

  // prologue: tile0 all 4 halves (dbuf0), tile1 A0,B0 (dbuf1); keep 4 in flight
  stage(0, 0, 0, 0); stage(0, 1, 0, 0); stage(0, 0, 1, 0); stage(0, 1, 1, 0);
  if (NT > 1) { stage(1, 0, 0, 1); stage(1, 1, 0, 1); }
  VMCNT4;
  BARRIER;

#pragma unroll 2
  for (int jt = 0; jt < NT; ++jt) {
    int d = jt & 1;
    // ph0: read A M0-3 + B N0-1; stage (jt+1, A1)
    rdA(d, 0); rdB(d, 0);
    if (jt + 1 < NT) stage(jt + 1, 0, 1, d ^ 1);
    BARRIER; LGKM0;
    quad(0, 0);
    BARRIER;
    // ph1: read A M4-7; stage (jt+1, B1)
    rdA(d, 4);
    if (jt + 1 < NT) stage(jt + 1, 1, 1, d ^ 1);
    BARRIER; LGKM0;
    quad(4, 0);
    BARRIER;
    // ph2: read B N2-3; stage (jt+2, A0)
    rdB(d, 2);
    if (jt + 2 < NT) stage(jt + 2, 0, 0, d);
    BARRIER; LGKM0;
    quad(0, 2);
    BARRIER;
    // ph3: stage (jt+2, B0); counted vmcnt (never 0 in-loop)
    if (jt + 2 < NT) stage(jt + 2, 1, 0, d);
    VMCNT4;
    BARRIER;
    quad(4, 2);
    BARRIER;
  }

  // epilogue: C layout col = lane&15, row = (lane>>4)*4 + reg
  int row0 = bm * 256 + wm * 128 + hi * 4;
  int col0 = bn * 256 + wn * 64 + lo;
  if (outBf16) {
    short* C = (short*)Cout;
#pragma unroll
    for (int m = 0; m < 8; ++m)
#pragma unroll
      for (int nf = 0; nf < 4; ++nf)
#pragma unroll
        for (int r = 0; r < 4; ++r)
          C[(size_t)(row0 + m * 16 + r) * N + col0 + nf * 16] = (short)f2bf(acc[m][nf][r]);
  } else {
    float* C = (float*)Cout;
#pragma unroll
    for (int m = 0; m < 8; ++m)
#pragma unroll
      for (int nf = 0; nf < 4; ++nf)
#pragma unroll
        for (int r = 0; r < 4; ++r)
          C[(size_t)(row0 + m * 16 + r) * N + col0 + nf * 16] = acc[m][nf][r];
  }
}

// ---------------- kernel: RMSNorm + RoPE for q (16 heads) and k ----------------
// 256 threads = 4 waves; each wave (64 lanes = D) handles one token
__global__ __launch_bounds__(256) void k_qk(const short* __restrict__ qkvb,
                                            const int* __restrict__ pos,
                                            const float* __restrict__ qw,
                                            const float* __restrict__ kw,
                                            short* __restrict__ qb,
                                            short* __restrict__ kb) {
  int bt = blockIdx.x * 4 + (threadIdx.x >> 6);    // b*4096 + t
  int t = bt & 4095, b = bt >> 12;
  int d = threadIdx.x & 63;                        // 0..63
  int j = d & 31;
  float invf = __expf((float)j * (-13.815510558f / 32.f));
  float sn, cs;
  sincosf((float)pos[t * 3 + (j % 3)] * invf, &sn, &cs);
  const short* base = qkvb + (size_t)bt * 1280;
  float wq = qw[d], wk = kw[d];

  auto rowproc = [&](float x, float w) -> float {
    float ss = x * x;
    ss += __shfl_xor(ss, 1);  ss += __shfl_xor(ss, 2);  ss += __shfl_xor(ss, 4);
    ss += __shfl_xor(ss, 8);  ss += __shfl_xor(ss, 16); ss += __shfl_xor(ss, 32);
    float xn = x * rsqrtf(ss * 0.015625f + 1e-6f) * w;
    float pr = __shfl_xor(xn, 32);                 // RoPE partner d +- 32
    return (d < 32) ? xn * cs - pr * sn : xn * cs + pr * sn;
  };
  {
    float x = bf2f((unsigned short)base[1024 + d]);
    kb[(size_t)bt * 64 + d] = (short)f2bf(rowproc(x, wk));
  }
#pragma unroll 4
  for (int hh = 0; hh < 16; ++hh) {
    float x = bf2f((unsigned short)base[hh * 64 + d]);
    qb[((size_t)((b * 16 + hh) * 4096 + t)) * 64 + d] = (short)f2bf(rowproc(x, wq));
  }
}

// ---------------- kernel: V slice of qkv -> vtg[b][64][4096] ----------------
__global__ __launch_bounds__(256) void k_vt(const short* __restrict__ qkvb,
                                            short* __restrict__ vtg) {
  __shared__ short ts[64][72];                     // 72: 16B-aligned rows
  int t0 = blockIdx.x * 64;
  int b = t0 >> 12, tl0 = t0 & 4095;
  int row = threadIdx.x >> 2, c4 = threadIdx.x & 3;
  const short* src = qkvb + (size_t)(t0 + row) * 1280 + 1088 + c4 * 16;
  *(short8*)&ts[row][c4 * 16]     = *(const short8*)src;
  *(short8*)&ts[row][c4 * 16 + 8] = *(const short8*)(src + 8);
  __syncthreads();
  short8 o0, o1;                                   // row = d, c4 = token group
#pragma unroll
  for (int jj = 0; jj < 8; ++jj) {
    o0[jj] = ts[c4 * 16 + jj][row];
    o1[jj] = ts[c4 * 16 + 8 + jj][row];
  }
  short* dst = vtg + (size_t)(b * 64 + row) * 4096 + tl0 + c4 * 16;
  *(short8*)dst = o0;
  *(short8*)(dst + 8) = o1;
}

// ---------------- kernel: blocked sliding-window attention (swapped QK^T) ----
// grid 2048 = (b, n, h fastest). 4 waves x 32 q-rows. Per-32-key-subtile
// online softmax keeps only one f32x16 S live -> no VGPR spill at 128-reg cap.
__global__ __launch_bounds__(256, 4) void k_attn(const short* __restrict__ qb,
                                                 const short* __restrict__ kb,
                                                 const short* __restrict__ vtg,
                                                 short* __restrict__ y) {
  __shared__ __align__(16) char smem[33792];
  short* ks  = (short*)smem;            // [128 key][64 d], chunk-XOR swizzled
  short* vts = (short*)(smem + 16384);  // [64 d][128 key], chunk-XOR swizzled
  int bid = blockIdx.x;
  int swz = (bid & 7) * 256 + (bid >> 3);          // XCD swizzle
  int h = swz & 15, n = (swz >> 4) & 31, b = swz >> 9;
  int tid = threadIdx.x, wid = tid >> 6, lane = tid & 63;
  int lo = lane & 31, hi = lane >> 5;

  // Q fragments (B-operand: col = q-row = lane&31, k-chunk = s*16 + hi*8)
  const short* qrow = qb + (size_t)((b * 16 + h) * 4096 + n * 128 + wid * 32 + lo) * 64;
  short8 aq[4];
#pragma unroll
  for (int s = 0; s < 4; ++s) aq[s] = *(const short8*)(qrow + s * 16 + hi * 8);

  f32x16 O0 = {}, O1 = {};                         // O^T: rows d / d+32, col q
  float mrun = -1e30f, lrun = 0.f;
  int qr = wid * 32 + lo;
  const float SC = 0.125f * 1.4426950408889634f;   // scale * log2(e)

  for (int hf = (n == 0) ? 1 : 0; hf < 2; ++hf) {  // n==0: half0 fully masked
    int tg = (n - 1 + hf) * 128;                   // first key token (within b)
    // stage K: LDS slot (r, dc) <- global chunk dc^(r&7)  (linear DMA dest)
#pragma unroll
    for (int p = 0; p < 4; ++p) {
      int idx = p * 256 + tid;
      int r = idx >> 3, dc = idx & 7;
      gload16(kb + (size_t)(b * 4096 + tg + r) * 64 + ((dc ^ (r & 7)) << 3),
              ks + idx * 8);
    }
    // stage V^T: LDS slot (dd, s) <- global key-chunk s^(dd&7)
#pragma unroll
    for (int p = 0; p < 4; ++p) {
      int idx = p * 256 + tid;
      int dd = idx >> 4, s = idx & 15;
      gload16(vtg + (size_t)(b * 64 + dd) * 4096 + tg + ((s ^ (dd & 7)) << 3),
              vts + idx * 8);
    }
    __syncthreads();

#pragma unroll
    for (int mt = 0; mt < 4; ++mt) {
      // S^T subtile = K(32 keys) * Q^T : one f32x16 live at a time
      f32x16 S = {};
      int r = mt * 32 + lo;
#pragma unroll
      for (int kst = 0; kst < 4; ++kst) {
        short8 kf = *(const short8*)&ks[r * 64 + ((((kst << 1) | hi) ^ (r & 7)) << 3)];
        S = mfma32(kf, aq[kst], S);
      }
      // mask + scale into log2 domain: key = 32*mt + (reg&3)+8*(reg>>2)+4*hi
#pragma unroll
      for (int rr = 0; rr < 16; ++rr) {
        int kg = hf * 128 + mt * 32 + (rr & 3) + ((rr >> 2) << 3) + (hi << 2);
        S[rr] = (kg >= qr && kg <= qr + 128) ? S[rr] * SC : -30000.f;
      }
      // online max with defer-rescale (T13): skip O-rescale if growth <= 8
      float pmax = S[0];
#pragma unroll
      for (int rr = 1; rr < 16; ++rr) pmax = fmaxf(pmax, S[rr]);
      pmax = fmaxf(pmax, __shfl_xor(pmax, 32));
      if (!__all(pmax - mrun <= 8.f)) {
        float mn = fmaxf(mrun, pmax);
        float al = exp2f(mrun - mn);
        lrun *= al; mrun = mn;
#pragma unroll
        for (int rr = 0; rr < 16; ++rr) { O0[rr] *= al; O1[rr] *= al; }
      }
      float ls = 0.f;
#pragma unroll
      for (int rr = 0; rr < 16; ++rr) { S[rr] = exp2f(S[rr] - mrun); ls += S[rr]; }
      ls += __shfl_xor(ls, 32);
      lrun += ls;
      // O^T += V^T * P : pack P^T B-fragments via cvt_pk + permlane32_swap
#pragma unroll
      for (int h2 = 0; h2 < 2; ++h2) {
        int b0 = h2 * 8;
        unsigned pk0 = cvtpk(S[b0 + 0], S[b0 + 1]);
        unsigned pk1 = cvtpk(S[b0 + 2], S[b0 + 3]);
        unsigned pk2 = cvtpk(S[b0 + 4], S[b0 + 5]);
        unsigned pk3 = cvtpk(S[b0 + 6], S[b0 + 7]);
        asm("v_permlane32_swap_b32 %0, %1" : "+v"(pk0), "+v"(pk2));
        asm("v_permlane32_swap_b32 %0, %1" : "+v"(pk1), "+v"(pk3));
        uint4v uw; uw.x = pk0; uw.y = pk1; uw.z = pk2; uw.w = pk3;
        short8 pb = __builtin_bit_cast(short8, uw);
        int kc = mt * 4 + h2 * 2 + hi;             // key chunk 0..15
        short8 vb0 = *(const short8*)&vts[lo * 128 + ((kc ^ (lo & 7)) << 3)];
        short8 vb1 = *(const short8*)&vts[(32 + lo) * 128 + ((kc ^ (lo & 7)) << 3)];
        O0 = mfma32(vb0, pb, O0);
        O1 = mfma32(vb1, pb, O1);
      }
    }
    __syncthreads();
  }

  // epilogue: O^T/l -> LDS transpose -> coalesced bf16 stores
  float inv = 1.f / lrun;
  float* ot = (float*)smem + wid * 2112;           // [64 d][33] per wave
#pragma unroll
  for (int r = 0; r < 16; ++r) {
    int d0 = (r & 3) + ((r >> 2) << 3) + (hi << 2);
    ot[d0 * 33 + lo]        = O0[r] * inv;
    ot[(d0 + 32) * 33 + lo] = O1[r] * inv;
  }
  __syncthreads();
  int tok = lane >> 3, dc = lane & 7;
#pragma unroll
  for (int g = 0; g < 4; ++g) {
    int q = g * 8 + tok;
    short8 o8;
#pragma unroll
    for (int jj = 0; jj < 8; ++jj)
      o8[jj] = (short)f2bf(ot[(dc * 8 + jj) * 33 + q]);
    *(short8*)&y[(size_t)(b * 4096 + n * 128 + wid * 32 + q) * 1024 + h * 64 + dc * 8] = o8;
  }
}

// ---------------- launch ----------------
extern "C" void kernel_launch(void* const* d_in, const int* in_sizes, int n_in,
                              void* d_out, int out_size, void* d_ws, size_t ws_size,
                              hipStream_t stream) {
  const float* x      = (const float*)d_in[0];
  const int*   pos    = (const int*)d_in[1];
  const float* w_attn = (const float*)d_in[2];
  const float* w_proj = (const float*)d_in[3];
  const float* qw     = (const float*)d_in[4];
  const float* kw     = (const float*)d_in[5];

  char* ws = (char*)d_ws;
  short* xb   = (short*)ws;                         // 33,554,432 B (aliased as y later)
  short* wabt = (short*)(ws + 33554432);            //  2,621,440 B (1280 x 1024)
  short* wpbt = (short*)(ws + 36175872);            //  2,097,152 B
  short* qkvb = (short*)(ws + 38273024);            // 41,943,040 B (16384 x 1280)
  short* qb2  = (short*)(ws + 80216064);            // 33,554,432 B
  short* kb2  = (short*)(ws + 113770496);           //  2,097,152 B
  short* vtg  = (short*)(ws + 115867648);           //  2,097,152 B (total 112.5 MiB)
  short* ybuf = xb;                                 // xb dead after qkv GEMM

  hipLaunchKernelGGL(k_cvt, dim3(16384), dim3(256), 0, stream, x, xb, 4194304);
  hipLaunchKernelGGL(k_tcvt, dim3(32, 36), dim3(256), 0, stream, w_attn, wabt, 1024, 1152);
  hipLaunchKernelGGL(k_tcvt, dim3(32, 32), dim3(256), 0, stream, w_proj, wpbt, 1024, 1024);
  hipLaunchKernelGGL(k_gemm256, dim3(320), dim3(512), 0, stream, xb, wabt, (void*)qkvb,
                     16384, 1280, 1024, 1);
  hipLaunchKernelGGL(k_qk, dim3(4096), dim3(256), 0, stream, qkvb, pos, qw, kw, qb2, kb2);
  hipLaunchKernelGGL(k_vt, dim3(256), dim3(256), 0, stream, qkvb, vtg);
  hipLaunchKernelGGL(k_attn, dim3(2048), dim3(256), 0, stream, qb2, kb2, vtg, ybuf);
  hipLaunchKernelGGL(k_gemm256, dim3(256), dim3(512), 0, stream, ybuf, wpbt, d_out,
                     16384, 1024, 1024, 0);
}